// Round 10
// baseline (496.615 us; speedup 1.0000x reference)
//
#include <hip/hip_runtime.h>
#include <math.h>

#define NN 50000
#define NE 800000
#define NBK ((NN + 255) >> 8)   // 196 dst-buckets

__device__ __forceinline__ float selu_f(float x) {
    const float scale = 1.0507009873554805f;
    const float alpha = 1.6732632423543772f;
    return scale * (x > 0.0f ? x : alpha * expm1f(x));
}

// bf16 pack/unpack (RNE). low 16 = even element, high 16 = odd element.
__device__ __forceinline__ unsigned rnd_bf16(float f) {
    unsigned u = __float_as_uint(f);
    return (u + 0x7fffu + ((u >> 16) & 1u)) >> 16;
}
__device__ __forceinline__ unsigned pack_pair(float a, float b) {
    return (rnd_bf16(b) << 16) | rnd_bf16(a);
}
__device__ __forceinline__ float lo_f(unsigned u) { return __uint_as_float(u << 16); }
__device__ __forceinline__ float hi_f(unsigned u) { return __uint_as_float(u & 0xffff0000u); }

__global__ void k_init_cnt(int* cnt) {
    int i = blockIdx.x * blockDim.x + threadIdx.x;
    if (i < NN) cnt[i] = 0;
}

__global__ void k_hist(const int* __restrict__ dst, int* __restrict__ cnt) {
    int e = blockIdx.x * blockDim.x + threadIdx.x;
    if (e < NE) atomicAdd(&cnt[dst[e]], 1);
}

// ---- two-level exclusive scan over cnt -> rowptr (+ dinv fused) --------
#define NB1 ((NN + 1023) / 1024)

__global__ void k_scanA(const int* __restrict__ cnt, int* __restrict__ rowptr,
                        int* __restrict__ partials, float* __restrict__ dinv) {
    __shared__ int wsum[4];
    int tid = threadIdx.x;
    int lane = tid & 63, wave = tid >> 6;
    int base = blockIdx.x * 1024 + tid * 4;
    int e0 = 0, e1 = 0, e2 = 0, e3 = 0;
    if (base + 3 < NN) {
        int4 v = *(const int4*)&cnt[base];
        e0 = v.x; e1 = v.y; e2 = v.z; e3 = v.w;
    } else {
        if (base + 0 < NN) e0 = cnt[base + 0];
        if (base + 1 < NN) e1 = cnt[base + 1];
        if (base + 2 < NN) e2 = cnt[base + 2];
        if (base + 3 < NN) e3 = cnt[base + 3];
    }
    // fused dinv = rsqrt(deg+1)
    if (base + 0 < NN) dinv[base + 0] = rsqrtf((float)(e0 + 1));
    if (base + 1 < NN) dinv[base + 1] = rsqrtf((float)(e1 + 1));
    if (base + 2 < NN) dinv[base + 2] = rsqrtf((float)(e2 + 1));
    if (base + 3 < NN) dinv[base + 3] = rsqrtf((float)(e3 + 1));

    int lsum = e0 + e1 + e2 + e3;
    int s = lsum;
    #pragma unroll
    for (int off = 1; off < 64; off <<= 1) {
        int t = __shfl_up(s, off, 64);
        if (lane >= off) s += t;
    }
    if (lane == 63) wsum[wave] = s;
    __syncthreads();
    int wbase = 0;
    #pragma unroll
    for (int w = 0; w < 4; w++) wbase += (w < wave) ? wsum[w] : 0;
    int excl = wbase + s - lsum;
    if (base + 0 < NN) rowptr[base + 0] = excl;
    if (base + 1 < NN) rowptr[base + 1] = excl + e0;
    if (base + 2 < NN) rowptr[base + 2] = excl + e0 + e1;
    if (base + 3 < NN) rowptr[base + 3] = excl + e0 + e1 + e2;
    if (tid == 0)
        partials[blockIdx.x] = wsum[0] + wsum[1] + wsum[2] + wsum[3];
}

__global__ void k_scanB(int* __restrict__ partials, int* __restrict__ partials2,
                        int* __restrict__ rowptr) {
    int lane = threadIdx.x;
    int v = (lane < NB1) ? partials[lane] : 0;
    int s = v;
    #pragma unroll
    for (int off = 1; off < 64; off <<= 1) {
        int t = __shfl_up(s, off, 64);
        if (lane >= off) s += t;
    }
    if (lane < NB1) partials2[lane] = s - v;  // exclusive
    if (lane == 63) rowptr[NN] = s;           // grand total
}

// rowptr += offset; pos = rowptr; bucket cursors bpos[b] = rowptr[b<<8]
__global__ void k_scanC(int* __restrict__ rowptr, int* __restrict__ pos,
                        const int* __restrict__ partials2, int* __restrict__ bpos) {
    int off = partials2[blockIdx.x];
    int base = blockIdx.x * 1024 + threadIdx.x * 4;
    #pragma unroll
    for (int j = 0; j < 4; j++) {
        int idx = base + j;
        if (idx < NN) {
            int r = rowptr[idx] + off;
            rowptr[idx] = r;
            pos[idx] = r;
            if ((idx & 255) == 0) bpos[(idx >> 8) * 16] = r;  // padded cursors
        }
    }
}

// pass A: bin edges by dst>>8; writes are 196 sequential fronts
__global__ void k_bucketA(const int* __restrict__ src, const int* __restrict__ dst,
                          int* __restrict__ bpos, int2* __restrict__ tmp) {
    int e = blockIdx.x * blockDim.x + threadIdx.x;
    if (e < NE) {
        int s = src[e], d = dst[e];
        int slot = atomicAdd(&bpos[(d >> 8) * 16], 1);
        tmp[slot] = make_int2(s, d);
    }
}

// pass B: sequential read; final per-node scatter (writes L2-local per bucket)
__global__ void k_bucketB(const int2* __restrict__ tmp, const float* __restrict__ dinv,
                          int* __restrict__ pos, int2* __restrict__ edat) {
    int e = blockIdx.x * blockDim.x + threadIdx.x;
    if (e < NE) {
        int2 m = tmp[e];
        float nm = dinv[m.x] * dinv[m.y];
        int slot = atomicAdd(&pos[m.y], 1);
        edat[slot] = make_int2(m.x, __float_as_int(nm));
    }
}

// ---- bf16-LDS register-tiled matmul -> packed-bf16 table ---------------
// in: f32 (INF32) or packed-bf16 rows; W: f32; out: packed bf16, stride J/2.
template <int K, int J, bool INF32>
__global__ void __launch_bounds__(256) k_mm3(const void* __restrict__ in_,
                                             const float* __restrict__ W,
                                             unsigned* __restrict__ out) {
    constexpr int J2 = J / 2, K2 = K / 2;
    constexpr int CG = J / 4;          // 4 cols per thread
    constexpr int RG = 256 / CG;
    constexpr int RPT = 64 / RG;       // rows per thread (tile = 64 rows)
    constexpr int RS_STRIDE = K2 + 1;  // +1 uint pad: rg groups hit distinct banks

    __shared__ unsigned Ws_u[K * J2];
    __shared__ unsigned Rs_u[64 * RS_STRIDE];

    // stage W packed along j
    constexpr int NWF = K * J2 / 4;
    for (int f = threadIdx.x; f < NWF; f += 256) {
        int k = f / (J / 8), js = f % (J / 8);
        const float4* wp = (const float4*)&W[k * J + js * 8];
        float4 a = wp[0], b = wp[1];
        uint4 u;
        u.x = pack_pair(a.x, a.y); u.y = pack_pair(a.z, a.w);
        u.z = pack_pair(b.x, b.y); u.w = pack_pair(b.z, b.w);
        *(uint4*)&Ws_u[k * J2 + js * 4] = u;
    }

    const int cg = threadIdx.x % CG;
    const int rg = threadIdx.x / CG;
    const int row0 = blockIdx.x * 64;

    __syncthreads();
    // stage 64 rows, packed along k
    constexpr int NRF = 64 * K2 / 4;
    for (int f = threadIdx.x; f < NRF; f += 256) {
        int r = f / (K / 8), seg = f % (K / 8);
        int rr = row0 + r;
        if (rr < NN) {
            uint4 u;
            if constexpr (INF32) {
                const float4* ip = (const float4*)((const float*)in_ + (size_t)rr * K + seg * 8);
                float4 a = ip[0], b = ip[1];
                u.x = pack_pair(a.x, a.y); u.y = pack_pair(a.z, a.w);
                u.z = pack_pair(b.x, b.y); u.w = pack_pair(b.z, b.w);
            } else {
                u = *(const uint4*)((const unsigned*)in_ + (size_t)rr * K2 + seg * 4);
            }
            int base = r * RS_STRIDE + seg * 4;
            Rs_u[base + 0] = u.x; Rs_u[base + 1] = u.y;
            Rs_u[base + 2] = u.z; Rs_u[base + 3] = u.w;
        }
    }
    __syncthreads();

    float acc[RPT][4];
    #pragma unroll
    for (int r = 0; r < RPT; r++)
        acc[r][0] = acc[r][1] = acc[r][2] = acc[r][3] = 0.f;

    #pragma unroll 4
    for (int kk2 = 0; kk2 < K2; kk2++) {
        uint2 wa = *(const uint2*)&Ws_u[(2 * kk2) * J2 + 2 * cg];
        uint2 wb = *(const uint2*)&Ws_u[(2 * kk2 + 1) * J2 + 2 * cg];
        float we0 = lo_f(wa.x), we1 = hi_f(wa.x), we2 = lo_f(wa.y), we3 = hi_f(wa.y);
        float wo0 = lo_f(wb.x), wo1 = hi_f(wb.x), wo2 = lo_f(wb.y), wo3 = hi_f(wb.y);
        #pragma unroll
        for (int r = 0; r < RPT; r++) {
            unsigned u = Rs_u[(rg * RPT + r) * RS_STRIDE + kk2];
            float ae = lo_f(u), ao = hi_f(u);
            acc[r][0] += ae * we0; acc[r][0] += ao * wo0;
            acc[r][1] += ae * we1; acc[r][1] += ao * wo1;
            acc[r][2] += ae * we2; acc[r][2] += ao * wo2;
            acc[r][3] += ae * we3; acc[r][3] += ao * wo3;
        }
    }

    #pragma unroll
    for (int r = 0; r < RPT; r++) {
        int row = row0 + rg * RPT + r;
        if (row < NN) {
            uint2 p;
            p.x = pack_pair(acc[r][0], acc[r][1]);
            p.y = pack_pair(acc[r][2], acc[r][3]);
            *(uint2*)&out[(size_t)row * J2 + 2 * cg] = p;
        }
    }
}

// ---- 128-dim agg: one wave per node; lane owns dims (2L, 2L+1) ---------
template <bool DO_SELU, bool PACK>
__global__ void k_agg128(const unsigned* __restrict__ tab, const int* __restrict__ rowptr,
                         const int2* __restrict__ edat, const float* __restrict__ dinv,
                         const float* __restrict__ bias, void* __restrict__ out_) {
    int n = (blockIdx.x * blockDim.x + threadIdx.x) >> 6;
    int lane = threadIdx.x & 63;
    if (n >= NN) return;
    float dn = dinv[n];
    float self = dn * dn;
    int beg = rowptr[n], end = rowptr[n + 1];

    float2 bv = ((const float2*)bias)[lane];
    unsigned su = tab[(size_t)n * 64 + lane];
    float ax = bv.x + self * lo_f(su);
    float ay = bv.y + self * hi_f(su);

    int e = beg;
    for (; e + 7 < end; e += 8) {
        int2 m0 = edat[e + 0], m1 = edat[e + 1], m2 = edat[e + 2], m3 = edat[e + 3];
        int2 m4 = edat[e + 4], m5 = edat[e + 5], m6 = edat[e + 6], m7 = edat[e + 7];
        unsigned g0 = tab[(size_t)m0.x * 64 + lane];
        unsigned g1 = tab[(size_t)m1.x * 64 + lane];
        unsigned g2 = tab[(size_t)m2.x * 64 + lane];
        unsigned g3 = tab[(size_t)m3.x * 64 + lane];
        unsigned g4 = tab[(size_t)m4.x * 64 + lane];
        unsigned g5 = tab[(size_t)m5.x * 64 + lane];
        unsigned g6 = tab[(size_t)m6.x * 64 + lane];
        unsigned g7 = tab[(size_t)m7.x * 64 + lane];
        float w0 = __int_as_float(m0.y), w1 = __int_as_float(m1.y);
        float w2 = __int_as_float(m2.y), w3 = __int_as_float(m3.y);
        float w4 = __int_as_float(m4.y), w5 = __int_as_float(m5.y);
        float w6 = __int_as_float(m6.y), w7 = __int_as_float(m7.y);
        ax += w0 * lo_f(g0); ay += w0 * hi_f(g0);
        ax += w1 * lo_f(g1); ay += w1 * hi_f(g1);
        ax += w2 * lo_f(g2); ay += w2 * hi_f(g2);
        ax += w3 * lo_f(g3); ay += w3 * hi_f(g3);
        ax += w4 * lo_f(g4); ay += w4 * hi_f(g4);
        ax += w5 * lo_f(g5); ay += w5 * hi_f(g5);
        ax += w6 * lo_f(g6); ay += w6 * hi_f(g6);
        ax += w7 * lo_f(g7); ay += w7 * hi_f(g7);
    }
    for (; e < end; e++) {
        int2 m = edat[e];
        float w = __int_as_float(m.y);
        unsigned g = tab[(size_t)m.x * 64 + lane];
        ax += w * lo_f(g); ay += w * hi_f(g);
    }
    if constexpr (DO_SELU) { ax = selu_f(ax); ay = selu_f(ay); }
    if constexpr (PACK)
        ((unsigned*)out_)[(size_t)n * 64 + lane] = pack_pair(ax, ay);
    else
        ((float2*)out_)[(size_t)n * 64 + lane] = make_float2(ax, ay);
}

// ---- 64-dim agg: one wave per node, 2 edges in flight ------------------
template <bool DO_SELU, bool DO_NORM, bool PACK>
__global__ void k_agg64(const unsigned* __restrict__ tab, const int* __restrict__ rowptr,
                        const int2* __restrict__ edat, const float* __restrict__ dinv,
                        const float* __restrict__ bias, void* __restrict__ out_) {
    int n = (blockIdx.x * blockDim.x + threadIdx.x) >> 6;
    int lane = threadIdx.x & 63;
    if (n >= NN) return;
    int half = lane >> 5;
    int sub = lane & 31;
    float dn = dinv[n];
    float self = dn * dn;
    int beg = rowptr[n], end = rowptr[n + 1];

    float a0 = 0.f, a1 = 0.f;
    int e = beg + half;
    for (; e + 6 < end; e += 8) {
        int2 m0 = edat[e + 0], m1 = edat[e + 2], m2 = edat[e + 4], m3 = edat[e + 6];
        unsigned g0 = tab[(size_t)m0.x * 32 + sub];
        unsigned g1 = tab[(size_t)m1.x * 32 + sub];
        unsigned g2 = tab[(size_t)m2.x * 32 + sub];
        unsigned g3 = tab[(size_t)m3.x * 32 + sub];
        float w0 = __int_as_float(m0.y), w1 = __int_as_float(m1.y);
        float w2 = __int_as_float(m2.y), w3 = __int_as_float(m3.y);
        a0 += w0 * lo_f(g0); a1 += w0 * hi_f(g0);
        a0 += w1 * lo_f(g1); a1 += w1 * hi_f(g1);
        a0 += w2 * lo_f(g2); a1 += w2 * hi_f(g2);
        a0 += w3 * lo_f(g3); a1 += w3 * hi_f(g3);
    }
    for (; e < end; e += 2) {
        int2 m = edat[e];
        float w = __int_as_float(m.y);
        unsigned g = tab[(size_t)m.x * 32 + sub];
        a0 += w * lo_f(g); a1 += w * hi_f(g);
    }
    a0 += __shfl_xor(a0, 32);
    a1 += __shfl_xor(a1, 32);
    float2 bv = ((const float2*)bias)[sub];
    unsigned su = tab[(size_t)n * 32 + sub];
    a0 += bv.x + self * lo_f(su);
    a1 += bv.y + self * hi_f(su);
    if constexpr (DO_SELU) { a0 = selu_f(a0); a1 = selu_f(a1); }
    if constexpr (DO_NORM) {
        float ss = a0 * a0 + a1 * a1;
        #pragma unroll
        for (int off = 16; off > 0; off >>= 1) ss += __shfl_xor(ss, off);
        float nrm = sqrtf(ss);
        float inv = 1.0f / fmaxf(nrm, 1e-12f);
        a0 *= inv; a1 *= inv;
    }
    if (half == 0) {
        if constexpr (PACK)
            ((unsigned*)out_)[(size_t)n * 32 + sub] = pack_pair(a0, a1);
        else
            ((float2*)out_)[(size_t)n * 32 + sub] = make_float2(a0, a1);
    }
}

extern "C" void kernel_launch(void* const* d_in, const int* in_sizes, int n_in,
                              void* d_out, int out_size, void* d_ws, size_t ws_size,
                              hipStream_t stream) {
    const float* x  = (const float*)d_in[0];
    const int* edge = (const int*)d_in[1];
    const float* W1 = (const float*)d_in[2]; const float* b1 = (const float*)d_in[3];
    const float* W2 = (const float*)d_in[4]; const float* b2 = (const float*)d_in[5];
    const float* W3 = (const float*)d_in[6]; const float* b3 = (const float*)d_in[7];
    const float* W4 = (const float*)d_in[8]; const float* b4 = (const float*)d_in[9];
    float* out = (float*)d_out;

    char* ws = (char*)d_ws;
    size_t off = 0;
    auto alloc = [&](size_t bytes) -> void* {
        void* p = ws + off;
        off = (off + bytes + 255) & ~(size_t)255;
        return p;
    };
    int*      cnt    = (int*)alloc((size_t)NN * 4);
    int*      rowptr = (int*)alloc((size_t)(NN + 1) * 4);
    int*      pos    = (int*)alloc((size_t)NN * 4);
    float*    dinv   = (float*)alloc((size_t)NN * 4);
    int2*     edat   = (int2*)alloc((size_t)NE * 8);
    int2*     tmp    = (int2*)alloc((size_t)NE * 8);
    unsigned* tab    = (unsigned*)alloc((size_t)NN * 64 * 4);
    unsigned* bufU   = (unsigned*)alloc((size_t)NN * 64 * 4);
    int*      part1  = (int*)alloc(64 * 4);
    int*      part2  = (int*)alloc(64 * 4);
    int*      bpos   = (int*)alloc((size_t)NBK * 16 * 4);

    const int* srcp = edge;
    const int* dstp = edge + NE;

    const int BN = (NN + 255) / 256;
    const int BE = (NE + 255) / 256;

    k_init_cnt<<<BN, 256, 0, stream>>>(cnt);
    k_hist<<<BE, 256, 0, stream>>>(dstp, cnt);
    k_scanA<<<NB1, 256, 0, stream>>>(cnt, rowptr, part1, dinv);
    k_scanB<<<1, 64, 0, stream>>>(part1, part2, rowptr);
    k_scanC<<<NB1, 256, 0, stream>>>(rowptr, pos, part2, bpos);
    k_bucketA<<<BE, 256, 0, stream>>>(srcp, dstp, bpos, tmp);
    k_bucketB<<<BE, 256, 0, stream>>>(tmp, dinv, pos, edat);

    const int AGG_B = (NN + 3) / 4;   // 4 waves/block, 1 wave/node
    const int MMT = (NN + 63) / 64;   // 64-row tiles

    // layer 1: x(128) -> 128, selu
    k_mm3<128, 128, true><<<MMT, 256, 0, stream>>>(x, W1, tab);
    k_agg128<true, true><<<AGG_B, 256, 0, stream>>>(tab, rowptr, edat, dinv, b1, bufU);
    // layer 2: 128 -> 128, selu
    k_mm3<128, 128, false><<<MMT, 256, 0, stream>>>(bufU, W2, tab);
    k_agg128<true, true><<<AGG_B, 256, 0, stream>>>(tab, rowptr, edat, dinv, b2, bufU);
    // layer 3: 128 -> 64, selu
    k_mm3<128, 64, false><<<MMT, 256, 0, stream>>>(bufU, W3, tab);
    k_agg64<true, false, true><<<AGG_B, 256, 0, stream>>>(tab, rowptr, edat, dinv, b3, bufU);
    // layer 4: 64 -> 64, no selu, L2-normalize, straight to d_out
    k_mm3<64, 64, false><<<MMT, 256, 0, stream>>>(bufU, W4, tab);
    k_agg64<false, true, false><<<AGG_B, 256, 0, stream>>>(tab, rowptr, edat, dinv, b4, out);
}

// Round 12
// 420.272 us; speedup vs baseline: 1.1817x; 1.1817x over previous
//
#include <hip/hip_runtime.h>
#include <math.h>

#define NN 50000
#define NE 800000
#define NBK ((NN + 255) >> 8)      // 196 dst-buckets (256 nodes each)
#define EPB 4096                    // edges per binA block
#define BINA_BLOCKS ((NE + EPB - 1) / EPB)   // 196
#define EPT (EPB / 256)             // 16 edges per thread

__device__ __forceinline__ float selu_f(float x) {
    const float scale = 1.0507009873554805f;
    const float alpha = 1.6732632423543772f;
    return scale * (x > 0.0f ? x : alpha * expm1f(x));
}

// bf16 pack/unpack (RNE). low 16 = even element, high 16 = odd element.
__device__ __forceinline__ unsigned rnd_bf16(float f) {
    unsigned u = __float_as_uint(f);
    return (u + 0x7fffu + ((u >> 16) & 1u)) >> 16;
}
__device__ __forceinline__ unsigned pack_pair(float a, float b) {
    return (rnd_bf16(b) << 16) | rnd_bf16(a);
}
__device__ __forceinline__ float lo_f(unsigned u) { return __uint_as_float(u << 16); }
__device__ __forceinline__ float hi_f(unsigned u) { return __uint_as_float(u & 0xffff0000u); }

__global__ void k_hist(const int* __restrict__ dst, int* __restrict__ cnt) {
    int e = blockIdx.x * blockDim.x + threadIdx.x;
    if (e < NE) atomicAdd(&cnt[dst[e]], 1);
}

// ---- two-level exclusive scan over cnt -> rowptr (+ dinv fused) --------
#define NB1 ((NN + 1023) / 1024)

__global__ void k_scanA(const int* __restrict__ cnt, int* __restrict__ rowptr,
                        int* __restrict__ partials, float* __restrict__ dinv) {
    __shared__ int wsum[4];
    int tid = threadIdx.x;
    int lane = tid & 63, wave = tid >> 6;
    int base = blockIdx.x * 1024 + tid * 4;
    int e0 = 0, e1 = 0, e2 = 0, e3 = 0;
    if (base + 3 < NN) {
        int4 v = *(const int4*)&cnt[base];
        e0 = v.x; e1 = v.y; e2 = v.z; e3 = v.w;
    } else {
        if (base + 0 < NN) e0 = cnt[base + 0];
        if (base + 1 < NN) e1 = cnt[base + 1];
        if (base + 2 < NN) e2 = cnt[base + 2];
        if (base + 3 < NN) e3 = cnt[base + 3];
    }
    if (base + 0 < NN) dinv[base + 0] = rsqrtf((float)(e0 + 1));
    if (base + 1 < NN) dinv[base + 1] = rsqrtf((float)(e1 + 1));
    if (base + 2 < NN) dinv[base + 2] = rsqrtf((float)(e2 + 1));
    if (base + 3 < NN) dinv[base + 3] = rsqrtf((float)(e3 + 1));

    int lsum = e0 + e1 + e2 + e3;
    int s = lsum;
    #pragma unroll
    for (int off = 1; off < 64; off <<= 1) {
        int t = __shfl_up(s, off, 64);
        if (lane >= off) s += t;
    }
    if (lane == 63) wsum[wave] = s;
    __syncthreads();
    int wbase = 0;
    #pragma unroll
    for (int w = 0; w < 4; w++) wbase += (w < wave) ? wsum[w] : 0;
    int excl = wbase + s - lsum;
    if (base + 0 < NN) rowptr[base + 0] = excl;
    if (base + 1 < NN) rowptr[base + 1] = excl + e0;
    if (base + 2 < NN) rowptr[base + 2] = excl + e0 + e1;
    if (base + 3 < NN) rowptr[base + 3] = excl + e0 + e1 + e2;
    if (tid == 0)
        partials[blockIdx.x] = wsum[0] + wsum[1] + wsum[2] + wsum[3];
}

__global__ void k_scanB(int* __restrict__ partials, int* __restrict__ partials2,
                        int* __restrict__ rowptr) {
    int lane = threadIdx.x;
    int v = (lane < NB1) ? partials[lane] : 0;
    int s = v;
    #pragma unroll
    for (int off = 1; off < 64; off <<= 1) {
        int t = __shfl_up(s, off, 64);
        if (lane >= off) s += t;
    }
    if (lane < NB1) partials2[lane] = s - v;  // exclusive
    if (lane == 63) rowptr[NN] = s;           // grand total
}

// rowptr += offset; bucket cursors bcur[b*16] = rowptr[b<<8] (64B-padded)
__global__ void k_scanC(int* __restrict__ rowptr, const int* __restrict__ partials2,
                        int* __restrict__ bcur) {
    int off = partials2[blockIdx.x];
    int base = blockIdx.x * 1024 + threadIdx.x * 4;
    #pragma unroll
    for (int j = 0; j < 4; j++) {
        int idx = base + j;
        if (idx < NN) {
            int r = rowptr[idx] + off;
            rowptr[idx] = r;
            if ((idx & 255) == 0) bcur[(idx >> 8) * 16] = r;
        }
    }
}

// ---- pass A: LDS-binned bucket sort; block-private contiguous runs -----
// tmp[slot] = (src<<8) | (dst & 255), bucket-major.
__global__ void __launch_bounds__(256) k_binA(const int* __restrict__ src,
                                              const int* __restrict__ dst,
                                              int* __restrict__ bcur,
                                              int* __restrict__ tmp) {
    __shared__ int hist[NBK];
    __shared__ int gbase[NBK];
    int tid = threadIdx.x;
    for (int i = tid; i < NBK; i += 256) hist[i] = 0;
    __syncthreads();

    const int e0 = blockIdx.x * EPB;
    int rec[EPT];
    int bs[EPT];
    #pragma unroll
    for (int j = 0; j < EPT; j++) {
        int e = e0 + j * 256 + tid;
        if (e < NE) {
            int s = src[e], d = dst[e];
            int b = d >> 8;
            int slot = atomicAdd(&hist[b], 1);
            rec[j] = (s << 8) | (d & 255);
            bs[j] = (b << 16) | slot;
        } else {
            bs[j] = -1;
        }
    }
    __syncthreads();
    for (int i = tid; i < NBK; i += 256)
        gbase[i] = atomicAdd(&bcur[i * 16], hist[i]);
    __syncthreads();
    #pragma unroll
    for (int j = 0; j < EPT; j++) {
        if (bs[j] >= 0) {
            int b = bs[j] >> 16, slot = bs[j] & 0xffff;
            tmp[gbase[b] + slot] = rec[j];
        }
    }
}

// ---- pass B: one block per bucket; LDS cursors; L2-local final scatter -
__global__ void __launch_bounds__(256) k_binB(const int* __restrict__ tmp,
                                              const int* __restrict__ rowptr,
                                              const float* __restrict__ dinv,
                                              int2* __restrict__ edat) {
    __shared__ int lpos[256];
    __shared__ float ldin[256];
    int b = blockIdx.x, tid = threadIdx.x;
    int n0 = b << 8;
    int n = n0 + tid;
    if (n < NN) { lpos[tid] = rowptr[n]; ldin[tid] = dinv[n]; }
    int base = rowptr[n0];
    int end  = rowptr[(n0 + 256 < NN) ? n0 + 256 : NN];
    __syncthreads();
    for (int i = base + tid; i < end; i += 256) {
        int rc = tmp[i];
        int s = rc >> 8;
        int dl = rc & 255;
        float nm = dinv[s] * ldin[dl];
        int slot = atomicAdd(&lpos[dl], 1);
        edat[slot] = make_int2(s, __float_as_int(nm));
    }
}

// ---- bf16-LDS register-tiled matmul -> packed-bf16 table ---------------
template <int K, int J, bool INF32>
__global__ void __launch_bounds__(256) k_mm3(const void* __restrict__ in_,
                                             const float* __restrict__ W,
                                             unsigned* __restrict__ out) {
    constexpr int J2 = J / 2, K2 = K / 2;
    constexpr int CG = J / 4;
    constexpr int RG = 256 / CG;
    constexpr int RPT = 64 / RG;
    constexpr int RS_STRIDE = K2 + 1;

    __shared__ unsigned Ws_u[K * J2];
    __shared__ unsigned Rs_u[64 * RS_STRIDE];

    constexpr int NWF = K * J2 / 4;
    for (int f = threadIdx.x; f < NWF; f += 256) {
        int k = f / (J / 8), js = f % (J / 8);
        const float4* wp = (const float4*)&W[k * J + js * 8];
        float4 a = wp[0], b = wp[1];
        uint4 u;
        u.x = pack_pair(a.x, a.y); u.y = pack_pair(a.z, a.w);
        u.z = pack_pair(b.x, b.y); u.w = pack_pair(b.z, b.w);
        *(uint4*)&Ws_u[k * J2 + js * 4] = u;
    }

    const int cg = threadIdx.x % CG;
    const int rg = threadIdx.x / CG;
    const int row0 = blockIdx.x * 64;

    __syncthreads();
    constexpr int NRF = 64 * K2 / 4;
    for (int f = threadIdx.x; f < NRF; f += 256) {
        int r = f / (K / 8), seg = f % (K / 8);
        int rr = row0 + r;
        if (rr < NN) {
            uint4 u;
            if constexpr (INF32) {
                const float4* ip = (const float4*)((const float*)in_ + (size_t)rr * K + seg * 8);
                float4 a = ip[0], b = ip[1];
                u.x = pack_pair(a.x, a.y); u.y = pack_pair(a.z, a.w);
                u.z = pack_pair(b.x, b.y); u.w = pack_pair(b.z, b.w);
            } else {
                u = *(const uint4*)((const unsigned*)in_ + (size_t)rr * K2 + seg * 4);
            }
            int base = r * RS_STRIDE + seg * 4;
            Rs_u[base + 0] = u.x; Rs_u[base + 1] = u.y;
            Rs_u[base + 2] = u.z; Rs_u[base + 3] = u.w;
        }
    }
    __syncthreads();

    float acc[RPT][4];
    #pragma unroll
    for (int r = 0; r < RPT; r++)
        acc[r][0] = acc[r][1] = acc[r][2] = acc[r][3] = 0.f;

    #pragma unroll 4
    for (int kk2 = 0; kk2 < K2; kk2++) {
        uint2 wa = *(const uint2*)&Ws_u[(2 * kk2) * J2 + 2 * cg];
        uint2 wb = *(const uint2*)&Ws_u[(2 * kk2 + 1) * J2 + 2 * cg];
        float we0 = lo_f(wa.x), we1 = hi_f(wa.x), we2 = lo_f(wa.y), we3 = hi_f(wa.y);
        float wo0 = lo_f(wb.x), wo1 = hi_f(wb.x), wo2 = lo_f(wb.y), wo3 = hi_f(wb.y);
        #pragma unroll
        for (int r = 0; r < RPT; r++) {
            unsigned u = Rs_u[(rg * RPT + r) * RS_STRIDE + kk2];
            float ae = lo_f(u), ao = hi_f(u);
            acc[r][0] += ae * we0; acc[r][0] += ao * wo0;
            acc[r][1] += ae * we1; acc[r][1] += ao * wo1;
            acc[r][2] += ae * we2; acc[r][2] += ao * wo2;
            acc[r][3] += ae * we3; acc[r][3] += ao * wo3;
        }
    }

    #pragma unroll
    for (int r = 0; r < RPT; r++) {
        int row = row0 + rg * RPT + r;
        if (row < NN) {
            uint2 p;
            p.x = pack_pair(acc[r][0], acc[r][1]);
            p.y = pack_pair(acc[r][2], acc[r][3]);
            *(uint2*)&out[(size_t)row * J2 + 2 * cg] = p;
        }
    }
}

// ---- 128-dim agg: one wave per node; lane owns dims (2L, 2L+1) ---------
template <bool DO_SELU, bool PACK>
__global__ void k_agg128(const unsigned* __restrict__ tab, const int* __restrict__ rowptr,
                         const int2* __restrict__ edat, const float* __restrict__ dinv,
                         const float* __restrict__ bias, void* __restrict__ out_) {
    int n = (blockIdx.x * blockDim.x + threadIdx.x) >> 6;
    int lane = threadIdx.x & 63;
    if (n >= NN) return;
    float dn = dinv[n];
    float self = dn * dn;
    int beg = rowptr[n], end = rowptr[n + 1];

    float2 bv = ((const float2*)bias)[lane];
    unsigned su = tab[(size_t)n * 64 + lane];
    float ax = bv.x + self * lo_f(su);
    float ay = bv.y + self * hi_f(su);

    int e = beg;
    for (; e + 7 < end; e += 8) {
        int2 m0 = edat[e + 0], m1 = edat[e + 1], m2 = edat[e + 2], m3 = edat[e + 3];
        int2 m4 = edat[e + 4], m5 = edat[e + 5], m6 = edat[e + 6], m7 = edat[e + 7];
        unsigned g0 = tab[(size_t)m0.x * 64 + lane];
        unsigned g1 = tab[(size_t)m1.x * 64 + lane];
        unsigned g2 = tab[(size_t)m2.x * 64 + lane];
        unsigned g3 = tab[(size_t)m3.x * 64 + lane];
        unsigned g4 = tab[(size_t)m4.x * 64 + lane];
        unsigned g5 = tab[(size_t)m5.x * 64 + lane];
        unsigned g6 = tab[(size_t)m6.x * 64 + lane];
        unsigned g7 = tab[(size_t)m7.x * 64 + lane];
        float w0 = __int_as_float(m0.y), w1 = __int_as_float(m1.y);
        float w2 = __int_as_float(m2.y), w3 = __int_as_float(m3.y);
        float w4 = __int_as_float(m4.y), w5 = __int_as_float(m5.y);
        float w6 = __int_as_float(m6.y), w7 = __int_as_float(m7.y);
        ax += w0 * lo_f(g0); ay += w0 * hi_f(g0);
        ax += w1 * lo_f(g1); ay += w1 * hi_f(g1);
        ax += w2 * lo_f(g2); ay += w2 * hi_f(g2);
        ax += w3 * lo_f(g3); ay += w3 * hi_f(g3);
        ax += w4 * lo_f(g4); ay += w4 * hi_f(g4);
        ax += w5 * lo_f(g5); ay += w5 * hi_f(g5);
        ax += w6 * lo_f(g6); ay += w6 * hi_f(g6);
        ax += w7 * lo_f(g7); ay += w7 * hi_f(g7);
    }
    for (; e < end; e++) {
        int2 m = edat[e];
        float w = __int_as_float(m.y);
        unsigned g = tab[(size_t)m.x * 64 + lane];
        ax += w * lo_f(g); ay += w * hi_f(g);
    }
    if constexpr (DO_SELU) { ax = selu_f(ax); ay = selu_f(ay); }
    if constexpr (PACK)
        ((unsigned*)out_)[(size_t)n * 64 + lane] = pack_pair(ax, ay);
    else
        ((float2*)out_)[(size_t)n * 64 + lane] = make_float2(ax, ay);
}

// ---- 64-dim agg: one wave per node, 2 edges in flight ------------------
template <bool DO_SELU, bool DO_NORM, bool PACK>
__global__ void k_agg64(const unsigned* __restrict__ tab, const int* __restrict__ rowptr,
                        const int2* __restrict__ edat, const float* __restrict__ dinv,
                        const float* __restrict__ bias, void* __restrict__ out_) {
    int n = (blockIdx.x * blockDim.x + threadIdx.x) >> 6;
    int lane = threadIdx.x & 63;
    if (n >= NN) return;
    int half = lane >> 5;
    int sub = lane & 31;
    float dn = dinv[n];
    float self = dn * dn;
    int beg = rowptr[n], end = rowptr[n + 1];

    float a0 = 0.f, a1 = 0.f;
    int e = beg + half;
    for (; e + 6 < end; e += 8) {
        int2 m0 = edat[e + 0], m1 = edat[e + 2], m2 = edat[e + 4], m3 = edat[e + 6];
        unsigned g0 = tab[(size_t)m0.x * 32 + sub];
        unsigned g1 = tab[(size_t)m1.x * 32 + sub];
        unsigned g2 = tab[(size_t)m2.x * 32 + sub];
        unsigned g3 = tab[(size_t)m3.x * 32 + sub];
        float w0 = __int_as_float(m0.y), w1 = __int_as_float(m1.y);
        float w2 = __int_as_float(m2.y), w3 = __int_as_float(m3.y);
        a0 += w0 * lo_f(g0); a1 += w0 * hi_f(g0);
        a0 += w1 * lo_f(g1); a1 += w1 * hi_f(g1);
        a0 += w2 * lo_f(g2); a1 += w2 * hi_f(g2);
        a0 += w3 * lo_f(g3); a1 += w3 * hi_f(g3);
    }
    for (; e < end; e += 2) {
        int2 m = edat[e];
        float w = __int_as_float(m.y);
        unsigned g = tab[(size_t)m.x * 32 + sub];
        a0 += w * lo_f(g); a1 += w * hi_f(g);
    }
    a0 += __shfl_xor(a0, 32);
    a1 += __shfl_xor(a1, 32);
    float2 bv = ((const float2*)bias)[sub];
    unsigned su = tab[(size_t)n * 32 + sub];
    a0 += bv.x + self * lo_f(su);
    a1 += bv.y + self * hi_f(su);
    if constexpr (DO_SELU) { a0 = selu_f(a0); a1 = selu_f(a1); }
    if constexpr (DO_NORM) {
        float ss = a0 * a0 + a1 * a1;
        #pragma unroll
        for (int off = 16; off > 0; off >>= 1) ss += __shfl_xor(ss, off);
        float nrm = sqrtf(ss);
        float inv = 1.0f / fmaxf(nrm, 1e-12f);
        a0 *= inv; a1 *= inv;
    }
    if (half == 0) {
        if constexpr (PACK)
            ((unsigned*)out_)[(size_t)n * 32 + sub] = pack_pair(a0, a1);
        else
            ((float2*)out_)[(size_t)n * 32 + sub] = make_float2(a0, a1);
    }
}

extern "C" void kernel_launch(void* const* d_in, const int* in_sizes, int n_in,
                              void* d_out, int out_size, void* d_ws, size_t ws_size,
                              hipStream_t stream) {
    const float* x  = (const float*)d_in[0];
    const int* edge = (const int*)d_in[1];
    const float* W1 = (const float*)d_in[2]; const float* b1 = (const float*)d_in[3];
    const float* W2 = (const float*)d_in[4]; const float* b2 = (const float*)d_in[5];
    const float* W3 = (const float*)d_in[6]; const float* b3 = (const float*)d_in[7];
    const float* W4 = (const float*)d_in[8]; const float* b4 = (const float*)d_in[9];
    float* out = (float*)d_out;

    char* ws = (char*)d_ws;
    size_t off = 0;
    auto alloc = [&](size_t bytes) -> void* {
        void* p = ws + off;
        off = (off + bytes + 255) & ~(size_t)255;
        return p;
    };
    int*      cnt    = (int*)alloc((size_t)NN * 4);
    int*      rowptr = (int*)alloc((size_t)(NN + 1) * 4);
    float*    dinv   = (float*)alloc((size_t)NN * 4);
    int*      tmp    = (int*)alloc((size_t)NE * 4);
    int2*     edat   = (int2*)alloc((size_t)NE * 8);
    unsigned* tab    = (unsigned*)alloc((size_t)NN * 64 * 4);
    unsigned* bufU   = (unsigned*)alloc((size_t)NN * 64 * 4);
    int*      part1  = (int*)alloc(64 * 4);
    int*      part2  = (int*)alloc(64 * 4);
    int*      bcur   = (int*)alloc((size_t)NBK * 16 * 4);

    const int* srcp = edge;
    const int* dstp = edge + NE;

    const int BE = (NE + 255) / 256;

    hipMemsetAsync(cnt, 0, (size_t)NN * 4, stream);
    k_hist<<<BE, 256, 0, stream>>>(dstp, cnt);
    k_scanA<<<NB1, 256, 0, stream>>>(cnt, rowptr, part1, dinv);
    k_scanB<<<1, 64, 0, stream>>>(part1, part2, rowptr);
    k_scanC<<<NB1, 256, 0, stream>>>(rowptr, part2, bcur);
    k_binA<<<BINA_BLOCKS, 256, 0, stream>>>(srcp, dstp, bcur, tmp);
    k_binB<<<NBK, 256, 0, stream>>>(tmp, rowptr, dinv, edat);

    const int AGG_B = (NN + 3) / 4;   // 4 waves/block, 1 wave/node
    const int MMT = (NN + 63) / 64;   // 64-row tiles

    // layer 1: x(128) -> 128, selu
    k_mm3<128, 128, true><<<MMT, 256, 0, stream>>>(x, W1, tab);
    k_agg128<true, true><<<AGG_B, 256, 0, stream>>>(tab, rowptr, edat, dinv, b1, bufU);
    // layer 2: 128 -> 128, selu
    k_mm3<128, 128, false><<<MMT, 256, 0, stream>>>(bufU, W2, tab);
    k_agg128<true, true><<<AGG_B, 256, 0, stream>>>(tab, rowptr, edat, dinv, b2, bufU);
    // layer 3: 128 -> 64, selu
    k_mm3<128, 64, false><<<MMT, 256, 0, stream>>>(bufU, W3, tab);
    k_agg64<true, false, true><<<AGG_B, 256, 0, stream>>>(tab, rowptr, edat, dinv, b3, bufU);
    // layer 4: 64 -> 64, no selu, L2-normalize, straight to d_out
    k_mm3<64, 64, false><<<MMT, 256, 0, stream>>>(bufU, W4, tab);
    k_agg64<false, true, false><<<AGG_B, 256, 0, stream>>>(tab, rowptr, edat, dinv, b4, out);
}

// Round 15
// 354.045 us; speedup vs baseline: 1.4027x; 1.1871x over previous
//
#include <hip/hip_runtime.h>
#include <math.h>

#define NN 50000
#define NE 800000
#define NBK ((NN + 255) >> 8)      // 196 dst-buckets (256 nodes each)
#define EPB 4096                    // edges per binA block
#define BINA_BLOCKS ((NE + EPB - 1) / EPB)   // 196
#define EPT (EPB / 256)             // 16 edges per thread

typedef __attribute__((ext_vector_type(8))) __bf16 bf16x8;
typedef __attribute__((ext_vector_type(4))) float f32x4;

__device__ __forceinline__ float selu_f(float x) {
    const float scale = 1.0507009873554805f;
    const float alpha = 1.6732632423543772f;
    return scale * (x > 0.0f ? x : alpha * expm1f(x));
}

// bf16 pack/unpack (RNE). low 16 = even element, high 16 = odd element.
__device__ __forceinline__ unsigned rnd_bf16(float f) {
    unsigned u = __float_as_uint(f);
    return (u + 0x7fffu + ((u >> 16) & 1u)) >> 16;
}
__device__ __forceinline__ unsigned pack_pair(float a, float b) {
    return (rnd_bf16(b) << 16) | rnd_bf16(a);
}
__device__ __forceinline__ float lo_f(unsigned u) { return __uint_as_float(u << 16); }
__device__ __forceinline__ float hi_f(unsigned u) { return __uint_as_float(u & 0xffff0000u); }

__global__ void k_hist(const int* __restrict__ dst, int* __restrict__ cnt) {
    int e = blockIdx.x * blockDim.x + threadIdx.x;
    if (e < NE) atomicAdd(&cnt[dst[e]], 1);
}

// ---- two-level exclusive scan over cnt -> rowptr (+ dinv fused) --------
#define NB1 ((NN + 1023) / 1024)

__global__ void k_scanA(const int* __restrict__ cnt, int* __restrict__ rowptr,
                        int* __restrict__ partials, float* __restrict__ dinv) {
    __shared__ int wsum[4];
    int tid = threadIdx.x;
    int lane = tid & 63, wave = tid >> 6;
    int base = blockIdx.x * 1024 + tid * 4;
    int e0 = 0, e1 = 0, e2 = 0, e3 = 0;
    if (base + 3 < NN) {
        int4 v = *(const int4*)&cnt[base];
        e0 = v.x; e1 = v.y; e2 = v.z; e3 = v.w;
    } else {
        if (base + 0 < NN) e0 = cnt[base + 0];
        if (base + 1 < NN) e1 = cnt[base + 1];
        if (base + 2 < NN) e2 = cnt[base + 2];
        if (base + 3 < NN) e3 = cnt[base + 3];
    }
    if (base + 0 < NN) dinv[base + 0] = rsqrtf((float)(e0 + 1));
    if (base + 1 < NN) dinv[base + 1] = rsqrtf((float)(e1 + 1));
    if (base + 2 < NN) dinv[base + 2] = rsqrtf((float)(e2 + 1));
    if (base + 3 < NN) dinv[base + 3] = rsqrtf((float)(e3 + 1));

    int lsum = e0 + e1 + e2 + e3;
    int s = lsum;
    #pragma unroll
    for (int off = 1; off < 64; off <<= 1) {
        int t = __shfl_up(s, off, 64);
        if (lane >= off) s += t;
    }
    if (lane == 63) wsum[wave] = s;
    __syncthreads();
    int wbase = 0;
    #pragma unroll
    for (int w = 0; w < 4; w++) wbase += (w < wave) ? wsum[w] : 0;
    int excl = wbase + s - lsum;
    if (base + 0 < NN) rowptr[base + 0] = excl;
    if (base + 1 < NN) rowptr[base + 1] = excl + e0;
    if (base + 2 < NN) rowptr[base + 2] = excl + e0 + e1;
    if (base + 3 < NN) rowptr[base + 3] = excl + e0 + e1 + e2;
    if (tid == 0)
        partials[blockIdx.x] = wsum[0] + wsum[1] + wsum[2] + wsum[3];
}

__global__ void k_scanB(int* __restrict__ partials, int* __restrict__ partials2,
                        int* __restrict__ rowptr) {
    int lane = threadIdx.x;
    int v = (lane < NB1) ? partials[lane] : 0;
    int s = v;
    #pragma unroll
    for (int off = 1; off < 64; off <<= 1) {
        int t = __shfl_up(s, off, 64);
        if (lane >= off) s += t;
    }
    if (lane < NB1) partials2[lane] = s - v;  // exclusive
    if (lane == 63) rowptr[NN] = s;           // grand total
}

// rowptr += offset; bucket cursors bcur[b*16] = rowptr[b<<8] (64B-padded)
__global__ void k_scanC(int* __restrict__ rowptr, const int* __restrict__ partials2,
                        int* __restrict__ bcur) {
    int off = partials2[blockIdx.x];
    int base = blockIdx.x * 1024 + threadIdx.x * 4;
    #pragma unroll
    for (int j = 0; j < 4; j++) {
        int idx = base + j;
        if (idx < NN) {
            int r = rowptr[idx] + off;
            rowptr[idx] = r;
            if ((idx & 255) == 0) bcur[(idx >> 8) * 16] = r;
        }
    }
}

// ---- pass A: LDS-binned bucket sort; block-private contiguous runs -----
__global__ void __launch_bounds__(256) k_binA(const int* __restrict__ src,
                                              const int* __restrict__ dst,
                                              int* __restrict__ bcur,
                                              int* __restrict__ tmp) {
    __shared__ int hist[NBK];
    __shared__ int gbase[NBK];
    int tid = threadIdx.x;
    for (int i = tid; i < NBK; i += 256) hist[i] = 0;
    __syncthreads();

    const int e0 = blockIdx.x * EPB;
    int rec[EPT];
    int bs[EPT];
    #pragma unroll
    for (int j = 0; j < EPT; j++) {
        int e = e0 + j * 256 + tid;
        if (e < NE) {
            int s = src[e], d = dst[e];
            int b = d >> 8;
            int slot = atomicAdd(&hist[b], 1);
            rec[j] = (s << 8) | (d & 255);
            bs[j] = (b << 16) | slot;
        } else {
            bs[j] = -1;
        }
    }
    __syncthreads();
    for (int i = tid; i < NBK; i += 256)
        gbase[i] = atomicAdd(&bcur[i * 16], hist[i]);
    __syncthreads();
    #pragma unroll
    for (int j = 0; j < EPT; j++) {
        if (bs[j] >= 0) {
            int b = bs[j] >> 16, slot = bs[j] & 0xffff;
            tmp[gbase[b] + slot] = rec[j];
        }
    }
}

// ---- pass B: one block per bucket; LDS cursors; L2-local final scatter -
__global__ void __launch_bounds__(256) k_binB(const int* __restrict__ tmp,
                                              const int* __restrict__ rowptr,
                                              const float* __restrict__ dinv,
                                              int2* __restrict__ edat) {
    __shared__ int lpos[256];
    __shared__ float ldin[256];
    int b = blockIdx.x, tid = threadIdx.x;
    int n0 = b << 8;
    int n = n0 + tid;
    if (n < NN) { lpos[tid] = rowptr[n]; ldin[tid] = dinv[n]; }
    int base = rowptr[n0];
    int end  = rowptr[(n0 + 256 < NN) ? n0 + 256 : NN];
    __syncthreads();
    for (int i = base + tid; i < end; i += 256) {
        int rc = tmp[i];
        int s = rc >> 8;
        int dl = rc & 255;
        float nm = dinv[s] * ldin[dl];
        int slot = atomicAdd(&lpos[dl], 1);
        edat[slot] = make_int2(s, __float_as_int(nm));
    }
}

// ---- pack f32 x -> bf16 table (layer-1 input) --------------------------
__global__ void k_packx(const float* __restrict__ x, unsigned* __restrict__ tabX) {
    long u = (long)blockIdx.x * 256 + threadIdx.x;   // one uint4 per thread
    if (u * 4 < (long)NN * 64) {
        const float4* ip = (const float4*)&x[u * 8];
        float4 a = ip[0], b = ip[1];
        uint4 o;
        o.x = pack_pair(a.x, a.y); o.y = pack_pair(a.z, a.w);
        o.z = pack_pair(b.x, b.y); o.w = pack_pair(b.z, b.w);
        *(uint4*)&tabX[u * 4] = o;
    }
}

// ---- MFMA matmul: packed-bf16 in (rows x K), f32 W (K x J) -> packed out
// Each wave: 32 rows x J cols. Block: 4 waves = 128 rows.
// A-frag: lane l holds A[row = l&15][k = (l>>4)*8 + j]  (8 contiguous bf16)
// B-frag: lane l holds B[k = (l>>4)*8 + j][col = l&15]  (from W^T in LDS)
// C/D:    col = lane&15, row = (lane>>4)*4 + reg   [m89-verified]
template <int K, int J>
__global__ void __launch_bounds__(256) k_mm4(const unsigned* __restrict__ tabin,
                                             const float* __restrict__ W,
                                             unsigned* __restrict__ out) {
    constexpr int K2 = K / 2;
    constexpr int STRIDE = K2 + 4;    // uints per col: 16B-aligned, bank-spread
    constexpr int CT = J / 16;        // col tiles
    constexpr int KC = K / 32;        // k chunks
    constexpr int J2 = J / 2;

    __shared__ unsigned Wt[J * STRIDE];

    // stage W^T packed bf16: Wt[col*STRIDE + kk] = pack(W[2kk][col], W[2kk+1][col])
    for (int u = threadIdx.x; u < J * K2; u += 256) {
        int col = u % J, kk = u / J;
        Wt[col * STRIDE + kk] = pack_pair(W[(2 * kk) * J + col], W[(2 * kk + 1) * J + col]);
    }
    __syncthreads();

    const int w = threadIdx.x >> 6, l = threadIdx.x & 63;
    const int lr = l & 15, lk = l >> 4;
    const long r0 = (long)blockIdx.x * 128 + w * 32;

    f32x4 acc[CT][2];
    #pragma unroll
    for (int t = 0; t < CT; t++) {
        acc[t][0] = (f32x4)(0.0f);
        acc[t][1] = (f32x4)(0.0f);
    }

    #pragma unroll
    for (int kc = 0; kc < KC; kc++) {
        uint4 a0u = *(const uint4*)&tabin[(r0 + lr) * K2 + kc * 16 + lk * 4];
        uint4 a1u = *(const uint4*)&tabin[(r0 + 16 + lr) * K2 + kc * 16 + lk * 4];
        bf16x8 a0 = __builtin_bit_cast(bf16x8, a0u);
        bf16x8 a1 = __builtin_bit_cast(bf16x8, a1u);
        #pragma unroll
        for (int t = 0; t < CT; t++) {
            uint4 bu = *(const uint4*)&Wt[(t * 16 + lr) * STRIDE + kc * 16 + lk * 4];
            bf16x8 b = __builtin_bit_cast(bf16x8, bu);
            acc[t][0] = __builtin_amdgcn_mfma_f32_16x16x32_bf16(a0, b, acc[t][0], 0, 0, 0);
            acc[t][1] = __builtin_amdgcn_mfma_f32_16x16x32_bf16(a1, b, acc[t][1], 0, 0, 0);
        }
    }

    // write packed pairs: lanes (l, l^1) hold adjacent cols of same rows
    #pragma unroll
    for (int t = 0; t < CT; t++) {
        #pragma unroll
        for (int s = 0; s < 2; s++) {
            f32x4 d = acc[t][s];
            #pragma unroll
            for (int i = 0; i < 4; i++) {
                float v = d[i];
                float vp = __shfl_xor(v, 1);
                long row = r0 + s * 16 + lk * 4 + i;
                if (!(l & 1) && row < NN)
                    out[row * J2 + t * 8 + (lr >> 1)] = pack_pair(v, vp);
            }
        }
    }
}

// ---- 128-dim agg: one wave per node; lane owns dims (2L, 2L+1) ---------
template <bool DO_SELU, bool PACK>
__global__ void k_agg128(const unsigned* __restrict__ tab, const int* __restrict__ rowptr,
                         const int2* __restrict__ edat, const float* __restrict__ dinv,
                         const float* __restrict__ bias, void* __restrict__ out_) {
    int n = (blockIdx.x * blockDim.x + threadIdx.x) >> 6;
    int lane = threadIdx.x & 63;
    if (n >= NN) return;
    float dn = dinv[n];
    float self = dn * dn;
    int beg = rowptr[n], end = rowptr[n + 1];

    float2 bv = ((const float2*)bias)[lane];
    unsigned su = tab[(size_t)n * 64 + lane];
    float ax = bv.x + self * lo_f(su);
    float ay = bv.y + self * hi_f(su);

    int e = beg;
    for (; e + 7 < end; e += 8) {
        int2 m0 = edat[e + 0], m1 = edat[e + 1], m2 = edat[e + 2], m3 = edat[e + 3];
        int2 m4 = edat[e + 4], m5 = edat[e + 5], m6 = edat[e + 6], m7 = edat[e + 7];
        unsigned g0 = tab[(size_t)m0.x * 64 + lane];
        unsigned g1 = tab[(size_t)m1.x * 64 + lane];
        unsigned g2 = tab[(size_t)m2.x * 64 + lane];
        unsigned g3 = tab[(size_t)m3.x * 64 + lane];
        unsigned g4 = tab[(size_t)m4.x * 64 + lane];
        unsigned g5 = tab[(size_t)m5.x * 64 + lane];
        unsigned g6 = tab[(size_t)m6.x * 64 + lane];
        unsigned g7 = tab[(size_t)m7.x * 64 + lane];
        float w0 = __int_as_float(m0.y), w1 = __int_as_float(m1.y);
        float w2 = __int_as_float(m2.y), w3 = __int_as_float(m3.y);
        float w4 = __int_as_float(m4.y), w5 = __int_as_float(m5.y);
        float w6 = __int_as_float(m6.y), w7 = __int_as_float(m7.y);
        ax += w0 * lo_f(g0); ay += w0 * hi_f(g0);
        ax += w1 * lo_f(g1); ay += w1 * hi_f(g1);
        ax += w2 * lo_f(g2); ay += w2 * hi_f(g2);
        ax += w3 * lo_f(g3); ay += w3 * hi_f(g3);
        ax += w4 * lo_f(g4); ay += w4 * hi_f(g4);
        ax += w5 * lo_f(g5); ay += w5 * hi_f(g5);
        ax += w6 * lo_f(g6); ay += w6 * hi_f(g6);
        ax += w7 * lo_f(g7); ay += w7 * hi_f(g7);
    }
    for (; e < end; e++) {
        int2 m = edat[e];
        float w = __int_as_float(m.y);
        unsigned g = tab[(size_t)m.x * 64 + lane];
        ax += w * lo_f(g); ay += w * hi_f(g);
    }
    if constexpr (DO_SELU) { ax = selu_f(ax); ay = selu_f(ay); }
    if constexpr (PACK)
        ((unsigned*)out_)[(size_t)n * 64 + lane] = pack_pair(ax, ay);
    else
        ((float2*)out_)[(size_t)n * 64 + lane] = make_float2(ax, ay);
}

// ---- 64-dim agg: one wave per node, 2 edges in flight ------------------
template <bool DO_SELU, bool DO_NORM, bool PACK>
__global__ void k_agg64(const unsigned* __restrict__ tab, const int* __restrict__ rowptr,
                        const int2* __restrict__ edat, const float* __restrict__ dinv,
                        const float* __restrict__ bias, void* __restrict__ out_) {
    int n = (blockIdx.x * blockDim.x + threadIdx.x) >> 6;
    int lane = threadIdx.x & 63;
    if (n >= NN) return;
    int half = lane >> 5;
    int sub = lane & 31;
    float dn = dinv[n];
    float self = dn * dn;
    int beg = rowptr[n], end = rowptr[n + 1];

    float a0 = 0.f, a1 = 0.f;
    int e = beg + half;
    for (; e + 6 < end; e += 8) {
        int2 m0 = edat[e + 0], m1 = edat[e + 2], m2 = edat[e + 4], m3 = edat[e + 6];
        unsigned g0 = tab[(size_t)m0.x * 32 + sub];
        unsigned g1 = tab[(size_t)m1.x * 32 + sub];
        unsigned g2 = tab[(size_t)m2.x * 32 + sub];
        unsigned g3 = tab[(size_t)m3.x * 32 + sub];
        float w0 = __int_as_float(m0.y), w1 = __int_as_float(m1.y);
        float w2 = __int_as_float(m2.y), w3 = __int_as_float(m3.y);
        a0 += w0 * lo_f(g0); a1 += w0 * hi_f(g0);
        a0 += w1 * lo_f(g1); a1 += w1 * hi_f(g1);
        a0 += w2 * lo_f(g2); a1 += w2 * hi_f(g2);
        a0 += w3 * lo_f(g3); a1 += w3 * hi_f(g3);
    }
    for (; e < end; e += 2) {
        int2 m = edat[e];
        float w = __int_as_float(m.y);
        unsigned g = tab[(size_t)m.x * 32 + sub];
        a0 += w * lo_f(g); a1 += w * hi_f(g);
    }
    a0 += __shfl_xor(a0, 32);
    a1 += __shfl_xor(a1, 32);
    float2 bv = ((const float2*)bias)[sub];
    unsigned su = tab[(size_t)n * 32 + sub];
    a0 += bv.x + self * lo_f(su);
    a1 += bv.y + self * hi_f(su);
    if constexpr (DO_SELU) { a0 = selu_f(a0); a1 = selu_f(a1); }
    if constexpr (DO_NORM) {
        float ss = a0 * a0 + a1 * a1;
        #pragma unroll
        for (int off = 16; off > 0; off >>= 1) ss += __shfl_xor(ss, off);
        float nrm = sqrtf(ss);
        float inv = 1.0f / fmaxf(nrm, 1e-12f);
        a0 *= inv; a1 *= inv;
    }
    if (half == 0) {
        if constexpr (PACK)
            ((unsigned*)out_)[(size_t)n * 32 + sub] = pack_pair(a0, a1);
        else
            ((float2*)out_)[(size_t)n * 32 + sub] = make_float2(a0, a1);
    }
}

extern "C" void kernel_launch(void* const* d_in, const int* in_sizes, int n_in,
                              void* d_out, int out_size, void* d_ws, size_t ws_size,
                              hipStream_t stream) {
    const float* x  = (const float*)d_in[0];
    const int* edge = (const int*)d_in[1];
    const float* W1 = (const float*)d_in[2]; const float* b1 = (const float*)d_in[3];
    const float* W2 = (const float*)d_in[4]; const float* b2 = (const float*)d_in[5];
    const float* W3 = (const float*)d_in[6]; const float* b3 = (const float*)d_in[7];
    const float* W4 = (const float*)d_in[8]; const float* b4 = (const float*)d_in[9];
    float* out = (float*)d_out;

    char* ws = (char*)d_ws;
    size_t off = 0;
    auto alloc = [&](size_t bytes) -> void* {
        void* p = ws + off;
        off = (off + bytes + 255) & ~(size_t)255;
        return p;
    };
    // table buffers padded by 128 rows: k_mm4's last block overreads harmlessly
    int*      cnt    = (int*)alloc((size_t)NN * 4);
    int*      rowptr = (int*)alloc((size_t)(NN + 1) * 4);
    float*    dinv   = (float*)alloc((size_t)NN * 4);
    int*      tmp    = (int*)alloc((size_t)NE * 4);
    int2*     edat   = (int2*)alloc((size_t)NE * 8);
    unsigned* tabX   = (unsigned*)alloc((size_t)(NN + 128) * 64 * 4);
    unsigned* tab    = (unsigned*)alloc((size_t)(NN + 128) * 64 * 4);
    unsigned* bufU   = (unsigned*)alloc((size_t)(NN + 128) * 64 * 4);
    int*      part1  = (int*)alloc(64 * 4);
    int*      part2  = (int*)alloc(64 * 4);
    int*      bcur   = (int*)alloc((size_t)NBK * 16 * 4);

    const int* srcp = edge;
    const int* dstp = edge + NE;

    const int BE = (NE + 255) / 256;

    hipMemsetAsync(cnt, 0, (size_t)NN * 4, stream);
    k_hist<<<BE, 256, 0, stream>>>(dstp, cnt);
    k_scanA<<<NB1, 256, 0, stream>>>(cnt, rowptr, part1, dinv);
    k_scanB<<<1, 64, 0, stream>>>(part1, part2, rowptr);
    k_scanC<<<NB1, 256, 0, stream>>>(rowptr, part2, bcur);
    k_binA<<<BINA_BLOCKS, 256, 0, stream>>>(srcp, dstp, bcur, tmp);
    k_binB<<<NBK, 256, 0, stream>>>(tmp, rowptr, dinv, edat);

    const int AGG_B = (NN + 3) / 4;       // 4 waves/block, 1 wave/node
    const int MMB = (NN + 127) / 128;     // 128-row MFMA tiles
    const int PXB = ((NN * 64 / 4) + 255) / 256;

    k_packx<<<PXB, 256, 0, stream>>>(x, tabX);

    // layer 1: x(128) -> 128, selu
    k_mm4<128, 128><<<MMB, 256, 0, stream>>>(tabX, W1, tab);
    k_agg128<true, true><<<AGG_B, 256, 0, stream>>>(tab, rowptr, edat, dinv, b1, bufU);
    // layer 2: 128 -> 128, selu
    k_mm4<128, 128><<<MMB, 256, 0, stream>>>(bufU, W2, tab);
    k_agg128<true, true><<<AGG_B, 256, 0, stream>>>(tab, rowptr, edat, dinv, b2, bufU);
    // layer 3: 128 -> 64, selu
    k_mm4<128, 64><<<MMB, 256, 0, stream>>>(bufU, W3, tab);
    k_agg64<true, false, true><<<AGG_B, 256, 0, stream>>>(tab, rowptr, edat, dinv, b3, bufU);
    // layer 4: 64 -> 64, no selu, L2-normalize, straight to d_out
    k_mm4<64, 64><<<MMB, 256, 0, stream>>>(bufU, W4, tab);
    k_agg64<false, true, false><<<AGG_B, 256, 0, stream>>>(tab, rowptr, edat, dinv, b4, out);
}

// Round 16
// 336.782 us; speedup vs baseline: 1.4746x; 1.0513x over previous
//
#include <hip/hip_runtime.h>
#include <math.h>

#define NN 50000
#define NE 800000
#define NBK ((NN + 255) >> 8)      // 196 dst-buckets (256 nodes each)
#define EPB 4096                    // edges per binA block
#define BINA_BLOCKS ((NE + EPB - 1) / EPB)   // 196
#define EPT (EPB / 256)             // 16 edges per thread

typedef __attribute__((ext_vector_type(8))) __bf16 bf16x8;
typedef __attribute__((ext_vector_type(4))) float f32x4;

__device__ __forceinline__ float selu_f(float x) {
    const float scale = 1.0507009873554805f;
    const float alpha = 1.6732632423543772f;
    return scale * (x > 0.0f ? x : alpha * expm1f(x));
}

// bf16 pack/unpack (RNE). low 16 = even element, high 16 = odd element.
__device__ __forceinline__ unsigned rnd_bf16(float f) {
    unsigned u = __float_as_uint(f);
    return (u + 0x7fffu + ((u >> 16) & 1u)) >> 16;
}
__device__ __forceinline__ unsigned pack_pair(float a, float b) {
    return (rnd_bf16(b) << 16) | rnd_bf16(a);
}
__device__ __forceinline__ float lo_f(unsigned u) { return __uint_as_float(u << 16); }
__device__ __forceinline__ float hi_f(unsigned u) { return __uint_as_float(u & 0xffff0000u); }

__global__ void k_hist(const int* __restrict__ dst, int* __restrict__ cnt) {
    int e = blockIdx.x * blockDim.x + threadIdx.x;
    if (e < NE) atomicAdd(&cnt[dst[e]], 1);
}

// ---- two-level exclusive scan over cnt -> rowptr (+ dinv fused) --------
#define NB1 ((NN + 1023) / 1024)

__global__ void k_scanA(const int* __restrict__ cnt, int* __restrict__ rowptr,
                        int* __restrict__ partials, float* __restrict__ dinv) {
    __shared__ int wsum[4];
    int tid = threadIdx.x;
    int lane = tid & 63, wave = tid >> 6;
    int base = blockIdx.x * 1024 + tid * 4;
    int e0 = 0, e1 = 0, e2 = 0, e3 = 0;
    if (base + 3 < NN) {
        int4 v = *(const int4*)&cnt[base];
        e0 = v.x; e1 = v.y; e2 = v.z; e3 = v.w;
    } else {
        if (base + 0 < NN) e0 = cnt[base + 0];
        if (base + 1 < NN) e1 = cnt[base + 1];
        if (base + 2 < NN) e2 = cnt[base + 2];
        if (base + 3 < NN) e3 = cnt[base + 3];
    }
    if (base + 0 < NN) dinv[base + 0] = rsqrtf((float)(e0 + 1));
    if (base + 1 < NN) dinv[base + 1] = rsqrtf((float)(e1 + 1));
    if (base + 2 < NN) dinv[base + 2] = rsqrtf((float)(e2 + 1));
    if (base + 3 < NN) dinv[base + 3] = rsqrtf((float)(e3 + 1));

    int lsum = e0 + e1 + e2 + e3;
    int s = lsum;
    #pragma unroll
    for (int off = 1; off < 64; off <<= 1) {
        int t = __shfl_up(s, off, 64);
        if (lane >= off) s += t;
    }
    if (lane == 63) wsum[wave] = s;
    __syncthreads();
    int wbase = 0;
    #pragma unroll
    for (int w = 0; w < 4; w++) wbase += (w < wave) ? wsum[w] : 0;
    int excl = wbase + s - lsum;
    if (base + 0 < NN) rowptr[base + 0] = excl;
    if (base + 1 < NN) rowptr[base + 1] = excl + e0;
    if (base + 2 < NN) rowptr[base + 2] = excl + e0 + e1;
    if (base + 3 < NN) rowptr[base + 3] = excl + e0 + e1 + e2;
    if (tid == 0)
        partials[blockIdx.x] = wsum[0] + wsum[1] + wsum[2] + wsum[3];
}

__global__ void k_scanB(int* __restrict__ partials, int* __restrict__ partials2,
                        int* __restrict__ rowptr) {
    int lane = threadIdx.x;
    int v = (lane < NB1) ? partials[lane] : 0;
    int s = v;
    #pragma unroll
    for (int off = 1; off < 64; off <<= 1) {
        int t = __shfl_up(s, off, 64);
        if (lane >= off) s += t;
    }
    if (lane < NB1) partials2[lane] = s - v;  // exclusive
    if (lane == 63) rowptr[NN] = s;           // grand total
}

// rowptr += offset; bucket cursors bcur[b*16] = rowptr[b<<8] (64B-padded)
__global__ void k_scanC(int* __restrict__ rowptr, const int* __restrict__ partials2,
                        int* __restrict__ bcur) {
    int off = partials2[blockIdx.x];
    int base = blockIdx.x * 1024 + threadIdx.x * 4;
    #pragma unroll
    for (int j = 0; j < 4; j++) {
        int idx = base + j;
        if (idx < NN) {
            int r = rowptr[idx] + off;
            rowptr[idx] = r;
            if ((idx & 255) == 0) bcur[(idx >> 8) * 16] = r;
        }
    }
}

// ---- pass A: LDS-binned bucket sort; block-private contiguous runs -----
__global__ void __launch_bounds__(256) k_binA(const int* __restrict__ src,
                                              const int* __restrict__ dst,
                                              int* __restrict__ bcur,
                                              int* __restrict__ tmp) {
    __shared__ int hist[NBK];
    __shared__ int gbase[NBK];
    int tid = threadIdx.x;
    for (int i = tid; i < NBK; i += 256) hist[i] = 0;
    __syncthreads();

    const int e0 = blockIdx.x * EPB;
    int rec[EPT];
    int bs[EPT];
    #pragma unroll
    for (int j = 0; j < EPT; j++) {
        int e = e0 + j * 256 + tid;
        if (e < NE) {
            int s = src[e], d = dst[e];
            int b = d >> 8;
            int slot = atomicAdd(&hist[b], 1);
            rec[j] = (s << 8) | (d & 255);
            bs[j] = (b << 16) | slot;
        } else {
            bs[j] = -1;
        }
    }
    __syncthreads();
    for (int i = tid; i < NBK; i += 256)
        gbase[i] = atomicAdd(&bcur[i * 16], hist[i]);
    __syncthreads();
    #pragma unroll
    for (int j = 0; j < EPT; j++) {
        if (bs[j] >= 0) {
            int b = bs[j] >> 16, slot = bs[j] & 0xffff;
            tmp[gbase[b] + slot] = rec[j];
        }
    }
}

// ---- pass B: one block per bucket; LDS cursors; L2-local final scatter -
__global__ void __launch_bounds__(256) k_binB(const int* __restrict__ tmp,
                                              const int* __restrict__ rowptr,
                                              const float* __restrict__ dinv,
                                              int2* __restrict__ edat) {
    __shared__ int lpos[256];
    __shared__ float ldin[256];
    int b = blockIdx.x, tid = threadIdx.x;
    int n0 = b << 8;
    int n = n0 + tid;
    if (n < NN) { lpos[tid] = rowptr[n]; ldin[tid] = dinv[n]; }
    int base = rowptr[n0];
    int end  = rowptr[(n0 + 256 < NN) ? n0 + 256 : NN];
    __syncthreads();
    for (int i = base + tid; i < end; i += 256) {
        int rc = tmp[i];
        int s = rc >> 8;
        int dl = rc & 255;
        float nm = dinv[s] * ldin[dl];
        int slot = atomicAdd(&lpos[dl], 1);
        edat[slot] = make_int2(s, __float_as_int(nm));
    }
}

// ---- pack f32 x -> bf16 table (layer-1 input) --------------------------
__global__ void k_packx(const float* __restrict__ x, unsigned* __restrict__ tabX) {
    long u = (long)blockIdx.x * 256 + threadIdx.x;   // one uint4 per thread
    if (u * 4 < (long)NN * 64) {
        const float4* ip = (const float4*)&x[u * 8];
        float4 a = ip[0], b = ip[1];
        uint4 o;
        o.x = pack_pair(a.x, a.y); o.y = pack_pair(a.z, a.w);
        o.z = pack_pair(b.x, b.y); o.w = pack_pair(b.z, b.w);
        *(uint4*)&tabX[u * 4] = o;
    }
}

// ---- pack all W^T into bf16 pairs: Wp[off + col*K2 + kk] ---------------
// L1: off 0 (J=128,K2=64)  L2: off 8192  L3: off 16384 (J=64,K2=64)
// L4: off 20480 (J=64,K2=32); total 22528 uints
__global__ void k_packw(const float* __restrict__ W1, const float* __restrict__ W2,
                        const float* __restrict__ W3, const float* __restrict__ W4,
                        unsigned* __restrict__ Wp) {
    int u = blockIdx.x * 256 + threadIdx.x;
    const float* W; int J, K2, off;
    if (u < 8192)       { W = W1; J = 128; K2 = 64; off = 0; }
    else if (u < 16384) { W = W2; J = 128; K2 = 64; off = 8192; }
    else if (u < 20480) { W = W3; J = 64;  K2 = 64; off = 16384; }
    else if (u < 22528) { W = W4; J = 64;  K2 = 32; off = 20480; }
    else return;
    int v = u - off;
    int col = v / K2, kk = v % K2;
    Wp[u] = pack_pair(W[(2 * kk) * J + col], W[(2 * kk + 1) * J + col]);
}

// ---- MFMA matmul: packed-bf16 in (rows x K), packed W^T -> packed out --
// A-frag: lane l holds A[row=l&15][k=(l>>4)*8+j]; B-frag from W^T in LDS.
// C/D: col=lane&15, row=(lane>>4)*4+reg  [m89-verified, passed R15]
template <int K, int J>
__global__ void __launch_bounds__(256) k_mm4(const unsigned* __restrict__ tabin,
                                             const unsigned* __restrict__ Wp,
                                             unsigned* __restrict__ out) {
    constexpr int K2 = K / 2;
    constexpr int STRIDE = K2 + 4;    // uints per col: 16B-aligned, bank-spread
    constexpr int CT = J / 16;        // col tiles
    constexpr int KC = K / 32;        // k chunks
    constexpr int J2 = J / 2;

    __shared__ unsigned Wt[J * STRIDE];

    // stage packed W^T: coalesced uint4 copies
    for (int u4 = threadIdx.x; u4 < J * K2 / 4; u4 += 256) {
        int v = u4 * 4;
        int col = v / K2, kk = v % K2;
        *(uint4*)&Wt[col * STRIDE + kk] = *(const uint4*)&Wp[v];
    }
    __syncthreads();

    const int w = threadIdx.x >> 6, l = threadIdx.x & 63;
    const int lr = l & 15, lk = l >> 4;
    const long r0 = (long)blockIdx.x * 128 + w * 32;

    f32x4 acc[CT][2];
    #pragma unroll
    for (int t = 0; t < CT; t++) {
        acc[t][0] = (f32x4)(0.0f);
        acc[t][1] = (f32x4)(0.0f);
    }

    #pragma unroll
    for (int kc = 0; kc < KC; kc++) {
        uint4 a0u = *(const uint4*)&tabin[(r0 + lr) * K2 + kc * 16 + lk * 4];
        uint4 a1u = *(const uint4*)&tabin[(r0 + 16 + lr) * K2 + kc * 16 + lk * 4];
        bf16x8 a0 = __builtin_bit_cast(bf16x8, a0u);
        bf16x8 a1 = __builtin_bit_cast(bf16x8, a1u);
        #pragma unroll
        for (int t = 0; t < CT; t++) {
            uint4 bu = *(const uint4*)&Wt[(t * 16 + lr) * STRIDE + kc * 16 + lk * 4];
            bf16x8 b = __builtin_bit_cast(bf16x8, bu);
            acc[t][0] = __builtin_amdgcn_mfma_f32_16x16x32_bf16(a0, b, acc[t][0], 0, 0, 0);
            acc[t][1] = __builtin_amdgcn_mfma_f32_16x16x32_bf16(a1, b, acc[t][1], 0, 0, 0);
        }
    }

    // write packed pairs: lanes (l, l^1) hold adjacent cols of same rows
    #pragma unroll
    for (int t = 0; t < CT; t++) {
        #pragma unroll
        for (int s = 0; s < 2; s++) {
            f32x4 d = acc[t][s];
            #pragma unroll
            for (int i = 0; i < 4; i++) {
                float v = d[i];
                float vp = __shfl_xor(v, 1);
                long row = r0 + s * 16 + lk * 4 + i;
                if (!(l & 1) && row < NN)
                    out[row * J2 + t * 8 + (lr >> 1)] = pack_pair(v, vp);
            }
        }
    }
}

// ---- 128-dim agg, wide: 16-lane group per edge, uint4 per lane ---------
template <bool DO_SELU>
__global__ void k_agg128w(const unsigned* __restrict__ tab, const int* __restrict__ rowptr,
                          const int2* __restrict__ edat, const float* __restrict__ dinv,
                          const float* __restrict__ bias, unsigned* __restrict__ outp) {
    int n = (blockIdx.x * blockDim.x + threadIdx.x) >> 6;
    int l = threadIdx.x & 63;
    if (n >= NN) return;
    int g = l >> 4, sub = l & 15;            // group = edge slot, sub = dim octet
    int beg = rowptr[n], end = rowptr[n + 1];

    float ax[8] = {0.f, 0.f, 0.f, 0.f, 0.f, 0.f, 0.f, 0.f};
    int e = beg + g;
    for (; e + 4 < end; e += 8) {            // 2 edges per group in flight
        int2 m0 = edat[e], m1 = edat[e + 4];
        uint4 v0 = *(const uint4*)&tab[(size_t)m0.x * 64 + sub * 4];
        uint4 v1 = *(const uint4*)&tab[(size_t)m1.x * 64 + sub * 4];
        float w0 = __int_as_float(m0.y), w1 = __int_as_float(m1.y);
        ax[0] += w0 * lo_f(v0.x); ax[1] += w0 * hi_f(v0.x);
        ax[2] += w0 * lo_f(v0.y); ax[3] += w0 * hi_f(v0.y);
        ax[4] += w0 * lo_f(v0.z); ax[5] += w0 * hi_f(v0.z);
        ax[6] += w0 * lo_f(v0.w); ax[7] += w0 * hi_f(v0.w);
        ax[0] += w1 * lo_f(v1.x); ax[1] += w1 * hi_f(v1.x);
        ax[2] += w1 * lo_f(v1.y); ax[3] += w1 * hi_f(v1.y);
        ax[4] += w1 * lo_f(v1.z); ax[5] += w1 * hi_f(v1.z);
        ax[6] += w1 * lo_f(v1.w); ax[7] += w1 * hi_f(v1.w);
    }
    for (; e < end; e += 4) {
        int2 m = edat[e];
        uint4 v = *(const uint4*)&tab[(size_t)m.x * 64 + sub * 4];
        float w = __int_as_float(m.y);
        ax[0] += w * lo_f(v.x); ax[1] += w * hi_f(v.x);
        ax[2] += w * lo_f(v.y); ax[3] += w * hi_f(v.y);
        ax[4] += w * lo_f(v.z); ax[5] += w * hi_f(v.z);
        ax[6] += w * lo_f(v.w); ax[7] += w * hi_f(v.w);
    }
    #pragma unroll
    for (int d = 0; d < 8; d++) {
        ax[d] += __shfl_xor(ax[d], 16);
        ax[d] += __shfl_xor(ax[d], 32);
    }
    if (g == 0) {
        float dn = dinv[n];
        float self = dn * dn;
        uint4 su = *(const uint4*)&tab[(size_t)n * 64 + sub * 4];
        float4 b0 = *(const float4*)&bias[sub * 8];
        float4 b1 = *(const float4*)&bias[sub * 8 + 4];
        ax[0] += b0.x + self * lo_f(su.x); ax[1] += b0.y + self * hi_f(su.x);
        ax[2] += b0.z + self * lo_f(su.y); ax[3] += b0.w + self * hi_f(su.y);
        ax[4] += b1.x + self * lo_f(su.z); ax[5] += b1.y + self * hi_f(su.z);
        ax[6] += b1.z + self * lo_f(su.w); ax[7] += b1.w + self * hi_f(su.w);
        if constexpr (DO_SELU) {
            #pragma unroll
            for (int d = 0; d < 8; d++) ax[d] = selu_f(ax[d]);
        }
        uint4 o;
        o.x = pack_pair(ax[0], ax[1]); o.y = pack_pair(ax[2], ax[3]);
        o.z = pack_pair(ax[4], ax[5]); o.w = pack_pair(ax[6], ax[7]);
        *(uint4*)&outp[(size_t)n * 64 + sub * 4] = o;
    }
}

// ---- 64-dim agg, wide: 8-lane group per edge, uint4 per lane -----------
template <bool DO_SELU, bool DO_NORM, bool PACK>
__global__ void k_agg64w(const unsigned* __restrict__ tab, const int* __restrict__ rowptr,
                         const int2* __restrict__ edat, const float* __restrict__ dinv,
                         const float* __restrict__ bias, void* __restrict__ out_) {
    int n = (blockIdx.x * blockDim.x + threadIdx.x) >> 6;
    int l = threadIdx.x & 63;
    if (n >= NN) return;
    int g = l >> 3, sub = l & 7;             // 8 groups x 8-dim octets
    int beg = rowptr[n], end = rowptr[n + 1];

    float ax[8] = {0.f, 0.f, 0.f, 0.f, 0.f, 0.f, 0.f, 0.f};
    int e = beg + g;
    for (; e + 8 < end; e += 16) {           // 2 edges per group in flight
        int2 m0 = edat[e], m1 = edat[e + 8];
        uint4 v0 = *(const uint4*)&tab[(size_t)m0.x * 32 + sub * 4];
        uint4 v1 = *(const uint4*)&tab[(size_t)m1.x * 32 + sub * 4];
        float w0 = __int_as_float(m0.y), w1 = __int_as_float(m1.y);
        ax[0] += w0 * lo_f(v0.x); ax[1] += w0 * hi_f(v0.x);
        ax[2] += w0 * lo_f(v0.y); ax[3] += w0 * hi_f(v0.y);
        ax[4] += w0 * lo_f(v0.z); ax[5] += w0 * hi_f(v0.z);
        ax[6] += w0 * lo_f(v0.w); ax[7] += w0 * hi_f(v0.w);
        ax[0] += w1 * lo_f(v1.x); ax[1] += w1 * hi_f(v1.x);
        ax[2] += w1 * lo_f(v1.y); ax[3] += w1 * hi_f(v1.y);
        ax[4] += w1 * lo_f(v1.z); ax[5] += w1 * hi_f(v1.z);
        ax[6] += w1 * lo_f(v1.w); ax[7] += w1 * hi_f(v1.w);
    }
    for (; e < end; e += 8) {
        int2 m = edat[e];
        uint4 v = *(const uint4*)&tab[(size_t)m.x * 32 + sub * 4];
        float w = __int_as_float(m.y);
        ax[0] += w * lo_f(v.x); ax[1] += w * hi_f(v.x);
        ax[2] += w * lo_f(v.y); ax[3] += w * hi_f(v.y);
        ax[4] += w * lo_f(v.z); ax[5] += w * hi_f(v.z);
        ax[6] += w * lo_f(v.w); ax[7] += w * hi_f(v.w);
    }
    #pragma unroll
    for (int d = 0; d < 8; d++) {
        ax[d] += __shfl_xor(ax[d], 8);
        ax[d] += __shfl_xor(ax[d], 16);
        ax[d] += __shfl_xor(ax[d], 32);
    }
    if (g == 0) {
        float dn = dinv[n];
        float self = dn * dn;
        uint4 su = *(const uint4*)&tab[(size_t)n * 32 + sub * 4];
        float4 b0 = *(const float4*)&bias[sub * 8];
        float4 b1 = *(const float4*)&bias[sub * 8 + 4];
        ax[0] += b0.x + self * lo_f(su.x); ax[1] += b0.y + self * hi_f(su.x);
        ax[2] += b0.z + self * lo_f(su.y); ax[3] += b0.w + self * hi_f(su.y);
        ax[4] += b1.x + self * lo_f(su.z); ax[5] += b1.y + self * hi_f(su.z);
        ax[6] += b1.z + self * lo_f(su.w); ax[7] += b1.w + self * hi_f(su.w);
        if constexpr (DO_SELU) {
            #pragma unroll
            for (int d = 0; d < 8; d++) ax[d] = selu_f(ax[d]);
        }
        if constexpr (DO_NORM) {
            float ss = 0.f;
            #pragma unroll
            for (int d = 0; d < 8; d++) ss += ax[d] * ax[d];
            ss += __shfl_xor(ss, 1);
            ss += __shfl_xor(ss, 2);
            ss += __shfl_xor(ss, 4);
            float inv = 1.0f / fmaxf(sqrtf(ss), 1e-12f);
            #pragma unroll
            for (int d = 0; d < 8; d++) ax[d] *= inv;
        }
        if constexpr (PACK) {
            uint4 o;
            o.x = pack_pair(ax[0], ax[1]); o.y = pack_pair(ax[2], ax[3]);
            o.z = pack_pair(ax[4], ax[5]); o.w = pack_pair(ax[6], ax[7]);
            *(uint4*)&((unsigned*)out_)[(size_t)n * 32 + sub * 4] = o;
        } else {
            float* op = (float*)out_ + (size_t)n * 64 + sub * 8;
            *(float4*)op = make_float4(ax[0], ax[1], ax[2], ax[3]);
            *(float4*)(op + 4) = make_float4(ax[4], ax[5], ax[6], ax[7]);
        }
    }
}

extern "C" void kernel_launch(void* const* d_in, const int* in_sizes, int n_in,
                              void* d_out, int out_size, void* d_ws, size_t ws_size,
                              hipStream_t stream) {
    const float* x  = (const float*)d_in[0];
    const int* edge = (const int*)d_in[1];
    const float* W1 = (const float*)d_in[2]; const float* b1 = (const float*)d_in[3];
    const float* W2 = (const float*)d_in[4]; const float* b2 = (const float*)d_in[5];
    const float* W3 = (const float*)d_in[6]; const float* b3 = (const float*)d_in[7];
    const float* W4 = (const float*)d_in[8]; const float* b4 = (const float*)d_in[9];
    float* out = (float*)d_out;

    char* ws = (char*)d_ws;
    size_t off = 0;
    auto alloc = [&](size_t bytes) -> void* {
        void* p = ws + off;
        off = (off + bytes + 255) & ~(size_t)255;
        return p;
    };
    // table buffers padded by 128 rows: k_mm4's last block overreads harmlessly
    int*      cnt    = (int*)alloc((size_t)NN * 4);
    int*      rowptr = (int*)alloc((size_t)(NN + 1) * 4);
    float*    dinv   = (float*)alloc((size_t)NN * 4);
    int*      tmp    = (int*)alloc((size_t)NE * 4);
    int2*     edat   = (int2*)alloc((size_t)NE * 8);
    unsigned* tabX   = (unsigned*)alloc((size_t)(NN + 128) * 64 * 4);
    unsigned* tab    = (unsigned*)alloc((size_t)(NN + 128) * 64 * 4);
    unsigned* bufU   = (unsigned*)alloc((size_t)(NN + 128) * 64 * 4);
    unsigned* Wp     = (unsigned*)alloc((size_t)22528 * 4);
    int*      part1  = (int*)alloc(64 * 4);
    int*      part2  = (int*)alloc(64 * 4);
    int*      bcur   = (int*)alloc((size_t)NBK * 16 * 4);

    const int* srcp = edge;
    const int* dstp = edge + NE;

    const int BE = (NE + 255) / 256;

    hipMemsetAsync(cnt, 0, (size_t)NN * 4, stream);
    k_hist<<<BE, 256, 0, stream>>>(dstp, cnt);
    k_scanA<<<NB1, 256, 0, stream>>>(cnt, rowptr, part1, dinv);
    k_scanB<<<1, 64, 0, stream>>>(part1, part2, rowptr);
    k_scanC<<<NB1, 256, 0, stream>>>(rowptr, part2, bcur);
    k_binA<<<BINA_BLOCKS, 256, 0, stream>>>(srcp, dstp, bcur, tmp);
    k_binB<<<NBK, 256, 0, stream>>>(tmp, rowptr, dinv, edat);

    const int AGG_B = (NN + 3) / 4;       // 4 waves/block, 1 wave/node
    const int MMB = (NN + 127) / 128;     // 128-row MFMA tiles
    const int PXB = ((NN * 64 / 4) + 255) / 256;

    k_packw<<<88, 256, 0, stream>>>(W1, W2, W3, W4, Wp);
    k_packx<<<PXB, 256, 0, stream>>>(x, tabX);

    // layer 1: x(128) -> 128, selu
    k_mm4<128, 128><<<MMB, 256, 0, stream>>>(tabX, Wp, tab);
    k_agg128w<true><<<AGG_B, 256, 0, stream>>>(tab, rowptr, edat, dinv, b1, bufU);
    // layer 2: 128 -> 128, selu
    k_mm4<128, 128><<<MMB, 256, 0, stream>>>(bufU, Wp + 8192, tab);
    k_agg128w<true><<<AGG_B, 256, 0, stream>>>(tab, rowptr, edat, dinv, b2, bufU);
    // layer 3: 128 -> 64, selu
    k_mm4<128, 64><<<MMB, 256, 0, stream>>>(bufU, Wp + 16384, tab);
    k_agg64w<true, false, true><<<AGG_B, 256, 0, stream>>>(tab, rowptr, edat, dinv, b3, bufU);
    // layer 4: 64 -> 64, no selu, L2-normalize, straight to d_out
    k_mm4<64, 64><<<MMB, 256, 0, stream>>>(bufU, Wp + 20480, tab);
    k_agg64w<false, true, false><<<AGG_B, 256, 0, stream>>>(tab, rowptr, edat, dinv, b4, out);
}

// Round 17
// 320.183 us; speedup vs baseline: 1.5510x; 1.0518x over previous
//
#include <hip/hip_runtime.h>
#include <math.h>

#define NN 50000
#define NE 800000
#define NBK ((NN + 255) >> 8)      // 196 dst-buckets (256 nodes each)
#define EPB 4096                    // edges per binA/histB block
#define BINA_BLOCKS ((NE + EPB - 1) / EPB)   // 196
#define EPT (EPB / 256)             // 16 edges per thread

typedef __attribute__((ext_vector_type(8))) __bf16 bf16x8;
typedef __attribute__((ext_vector_type(4))) float f32x4;

__device__ __forceinline__ float selu_f(float x) {
    const float scale = 1.0507009873554805f;
    const float alpha = 1.6732632423543772f;
    return scale * (x > 0.0f ? x : alpha * expm1f(x));
}

// bf16 pack/unpack (RNE). low 16 = even element, high 16 = odd element.
__device__ __forceinline__ unsigned rnd_bf16(float f) {
    unsigned u = __float_as_uint(f);
    return (u + 0x7fffu + ((u >> 16) & 1u)) >> 16;
}
__device__ __forceinline__ unsigned pack_pair(float a, float b) {
    return (rnd_bf16(b) << 16) | rnd_bf16(a);
}
__device__ __forceinline__ float lo_f(unsigned u) { return __uint_as_float(u << 16); }
__device__ __forceinline__ float hi_f(unsigned u) { return __uint_as_float(u & 0xffff0000u); }

// ---- 196-bucket histogram of dst>>8 (LDS-staged) -----------------------
__global__ void __launch_bounds__(256) k_histB(const int* __restrict__ dst,
                                               int* __restrict__ bhist) {
    __shared__ int h[NBK];
    for (int i = threadIdx.x; i < NBK; i += 256) h[i] = 0;
    __syncthreads();
    int e0 = blockIdx.x * EPB;
    #pragma unroll
    for (int j = 0; j < EPT; j++) {
        int e = e0 + j * 256 + threadIdx.x;
        if (e < NE) atomicAdd(&h[dst[e] >> 8], 1);
    }
    __syncthreads();
    for (int i = threadIdx.x; i < NBK; i += 256)
        if (h[i]) atomicAdd(&bhist[i], h[i]);
}

// ---- 1-block scan of bucket counts -> bbase, bcur ----------------------
__global__ void k_scanBkt(const int* __restrict__ bhist, int* __restrict__ bbase,
                          int* __restrict__ bcur, int* __restrict__ rowptr) {
    __shared__ int wsum[4];
    int tid = threadIdx.x;
    int lane = tid & 63, wave = tid >> 6;
    int v = (tid < NBK) ? bhist[tid] : 0;
    int s = v;
    #pragma unroll
    for (int off = 1; off < 64; off <<= 1) {
        int t = __shfl_up(s, off, 64);
        if (lane >= off) s += t;
    }
    if (lane == 63) wsum[wave] = s;
    __syncthreads();
    int wbase = 0;
    #pragma unroll
    for (int w = 0; w < 4; w++) wbase += (w < wave) ? wsum[w] : 0;
    int excl = wbase + s - v;
    if (tid < NBK) { bbase[tid] = excl; bcur[tid * 16] = excl; }
    if (tid == 0) { bbase[NBK] = NE; rowptr[NN] = NE; }
}

// ---- pass A: LDS-binned bucket sort; block-private contiguous runs -----
// tmp[slot] = (src<<8) | (dst & 255), bucket-major.
__global__ void __launch_bounds__(256) k_binA(const int* __restrict__ src,
                                              const int* __restrict__ dst,
                                              int* __restrict__ bcur,
                                              int* __restrict__ tmp) {
    __shared__ int hist[NBK];
    __shared__ int gbase[NBK];
    int tid = threadIdx.x;
    for (int i = tid; i < NBK; i += 256) hist[i] = 0;
    __syncthreads();

    const int e0 = blockIdx.x * EPB;
    int rec[EPT];
    int bs[EPT];
    #pragma unroll
    for (int j = 0; j < EPT; j++) {
        int e = e0 + j * 256 + tid;
        if (e < NE) {
            int s = src[e], d = dst[e];
            int b = d >> 8;
            int slot = atomicAdd(&hist[b], 1);
            rec[j] = (s << 8) | (d & 255);
            bs[j] = (b << 16) | slot;
        } else {
            bs[j] = -1;
        }
    }
    __syncthreads();
    for (int i = tid; i < NBK; i += 256)
        gbase[i] = atomicAdd(&bcur[i * 16], hist[i]);
    __syncthreads();
    #pragma unroll
    for (int j = 0; j < EPT; j++) {
        if (bs[j] >= 0) {
            int b = bs[j] >> 16, slot = bs[j] & 0xffff;
            tmp[gbase[b] + slot] = rec[j];
        }
    }
}

// ---- pass B: one block per bucket: count -> scan -> rowptr+dinv -> scatter
__global__ void __launch_bounds__(256) k_cntB(const int* __restrict__ tmp,
                                              const int* __restrict__ bbase,
                                              int* __restrict__ rowptr,
                                              float* __restrict__ dinv,
                                              int* __restrict__ ecol) {
    __shared__ int cnt256[256];
    __shared__ int lpos[256];
    __shared__ int wsum[4];
    int b = blockIdx.x, tid = threadIdx.x;
    int n0 = b << 8;
    cnt256[tid] = 0;
    __syncthreads();
    int base = bbase[b], end = bbase[b + 1];
    for (int i = base + tid; i < end; i += 256)
        atomicAdd(&cnt256[tmp[i] & 255], 1);
    __syncthreads();
    int c = cnt256[tid];
    int lane = tid & 63, wave = tid >> 6;
    int s = c;
    #pragma unroll
    for (int off = 1; off < 64; off <<= 1) {
        int t = __shfl_up(s, off, 64);
        if (lane >= off) s += t;
    }
    if (lane == 63) wsum[wave] = s;
    __syncthreads();
    int wbase = 0;
    #pragma unroll
    for (int w = 0; w < 4; w++) wbase += (w < wave) ? wsum[w] : 0;
    int excl = base + wbase + s - c;
    int n = n0 + tid;
    if (n < NN) {
        rowptr[n] = excl;
        dinv[n] = rsqrtf((float)(c + 1));
    }
    lpos[tid] = excl;
    __syncthreads();
    for (int i = base + tid; i < end; i += 256) {
        int rc = tmp[i];
        int slot = atomicAdd(&lpos[rc & 255], 1);
        ecol[slot] = rc >> 8;
    }
}

// ---- pack all W^T into bf16 pairs: Wp[off + col*K2 + kk] ---------------
__global__ void k_packw(const float* __restrict__ W1, const float* __restrict__ W2,
                        const float* __restrict__ W3, const float* __restrict__ W4,
                        unsigned* __restrict__ Wp) {
    int u = blockIdx.x * 256 + threadIdx.x;
    const float* W; int J, K2, off;
    if (u < 8192)       { W = W1; J = 128; K2 = 64; off = 0; }
    else if (u < 16384) { W = W2; J = 128; K2 = 64; off = 8192; }
    else if (u < 20480) { W = W3; J = 64;  K2 = 64; off = 16384; }
    else if (u < 22528) { W = W4; J = 64;  K2 = 32; off = 20480; }
    else return;
    int v = u - off;
    int col = v / K2, kk = v % K2;
    Wp[u] = pack_pair(W[(2 * kk) * J + col], W[(2 * kk + 1) * J + col]);
}

// ---- MFMA matmul; epilogue scales rows by dinv -> gather table ---------
// A-frag: lane l holds A[row=l&15][k=(l>>4)*8+j]; B-frag from W^T in LDS.
// C/D: col=lane&15, row=(lane>>4)*4+reg  [verified R15]
// INF32: read f32 rows (layer-1 x), clamp row index (MFMA C-rows map 1:1
// to A-rows, so clamped rows only affect discarded outputs >= NN).
template <int K, int J, bool INF32>
__global__ void __launch_bounds__(256) k_mm4(const void* __restrict__ in_,
                                             const unsigned* __restrict__ Wp,
                                             const float* __restrict__ dinv,
                                             unsigned* __restrict__ out) {
    constexpr int K2 = K / 2;
    constexpr int STRIDE = K2 + 4;
    constexpr int CT = J / 16;
    constexpr int KC = K / 32;
    constexpr int J2 = J / 2;

    __shared__ unsigned Wt[J * STRIDE];

    for (int u4 = threadIdx.x; u4 < J * K2 / 4; u4 += 256) {
        int v = u4 * 4;
        int col = v / K2, kk = v % K2;
        *(uint4*)&Wt[col * STRIDE + kk] = *(const uint4*)&Wp[v];
    }
    __syncthreads();

    const int w = threadIdx.x >> 6, l = threadIdx.x & 63;
    const int lr = l & 15, lk = l >> 4;
    const long r0 = (long)blockIdx.x * 128 + w * 32;

    f32x4 acc[CT][2];
    #pragma unroll
    for (int t = 0; t < CT; t++) {
        acc[t][0] = (f32x4)(0.0f);
        acc[t][1] = (f32x4)(0.0f);
    }

    #pragma unroll
    for (int kc = 0; kc < KC; kc++) {
        uint4 a0u, a1u;
        if constexpr (INF32) {
            const float* xin = (const float*)in_;
            long ra0 = r0 + lr;      if (ra0 >= NN) ra0 = NN - 1;
            long ra1 = r0 + 16 + lr; if (ra1 >= NN) ra1 = NN - 1;
            const float4* p0 = (const float4*)&xin[ra0 * K + kc * 32 + lk * 8];
            const float4* p1 = (const float4*)&xin[ra1 * K + kc * 32 + lk * 8];
            float4 fa = p0[0], fb = p0[1];
            a0u.x = pack_pair(fa.x, fa.y); a0u.y = pack_pair(fa.z, fa.w);
            a0u.z = pack_pair(fb.x, fb.y); a0u.w = pack_pair(fb.z, fb.w);
            float4 ga = p1[0], gb = p1[1];
            a1u.x = pack_pair(ga.x, ga.y); a1u.y = pack_pair(ga.z, ga.w);
            a1u.z = pack_pair(gb.x, gb.y); a1u.w = pack_pair(gb.z, gb.w);
        } else {
            const unsigned* tabin = (const unsigned*)in_;
            a0u = *(const uint4*)&tabin[(r0 + lr) * K2 + kc * 16 + lk * 4];
            a1u = *(const uint4*)&tabin[(r0 + 16 + lr) * K2 + kc * 16 + lk * 4];
        }
        bf16x8 a0 = __builtin_bit_cast(bf16x8, a0u);
        bf16x8 a1 = __builtin_bit_cast(bf16x8, a1u);
        #pragma unroll
        for (int t = 0; t < CT; t++) {
            uint4 bu = *(const uint4*)&Wt[(t * 16 + lr) * STRIDE + kc * 16 + lk * 4];
            bf16x8 b = __builtin_bit_cast(bf16x8, bu);
            acc[t][0] = __builtin_amdgcn_mfma_f32_16x16x32_bf16(a0, b, acc[t][0], 0, 0, 0);
            acc[t][1] = __builtin_amdgcn_mfma_f32_16x16x32_bf16(a1, b, acc[t][1], 0, 0, 0);
        }
    }

    // epilogue: scale row by dinv[row], pack pairs (lanes l,l^1: same rows)
    #pragma unroll
    for (int t = 0; t < CT; t++) {
        #pragma unroll
        for (int s = 0; s < 2; s++) {
            f32x4 d = acc[t][s];
            #pragma unroll
            for (int i = 0; i < 4; i++) {
                float v = d[i];
                float vp = __shfl_xor(v, 1);
                long row = r0 + s * 16 + lk * 4 + i;
                if (!(l & 1) && row < NN) {
                    float sc = dinv[row];
                    out[row * J2 + t * 8 + (lr >> 1)] = pack_pair(v * sc, vp * sc);
                }
            }
        }
    }
}

// ---- 128-dim agg, wide: 16-lane group per edge; unweighted gather-sum --
// tab rows are pre-scaled by dinv[src]; result scaled by dinv[n] once.
template <bool DO_SELU>
__global__ void k_agg128w(const unsigned* __restrict__ tab, const int* __restrict__ rowptr,
                          const int* __restrict__ ecol, const float* __restrict__ dinv,
                          const float* __restrict__ bias, unsigned* __restrict__ outp) {
    int n = (blockIdx.x * blockDim.x + threadIdx.x) >> 6;
    int l = threadIdx.x & 63;
    if (n >= NN) return;
    int g = l >> 4, sub = l & 15;
    int beg = rowptr[n], end = rowptr[n + 1];

    float ax[8] = {0.f, 0.f, 0.f, 0.f, 0.f, 0.f, 0.f, 0.f};
    int e = beg + g;
    for (; e + 4 < end; e += 8) {
        int s0 = ecol[e], s1 = ecol[e + 4];
        uint4 v0 = *(const uint4*)&tab[(size_t)s0 * 64 + sub * 4];
        uint4 v1 = *(const uint4*)&tab[(size_t)s1 * 64 + sub * 4];
        ax[0] += lo_f(v0.x); ax[1] += hi_f(v0.x);
        ax[2] += lo_f(v0.y); ax[3] += hi_f(v0.y);
        ax[4] += lo_f(v0.z); ax[5] += hi_f(v0.z);
        ax[6] += lo_f(v0.w); ax[7] += hi_f(v0.w);
        ax[0] += lo_f(v1.x); ax[1] += hi_f(v1.x);
        ax[2] += lo_f(v1.y); ax[3] += hi_f(v1.y);
        ax[4] += lo_f(v1.z); ax[5] += hi_f(v1.z);
        ax[6] += lo_f(v1.w); ax[7] += hi_f(v1.w);
    }
    for (; e < end; e += 4) {
        int s0 = ecol[e];
        uint4 v = *(const uint4*)&tab[(size_t)s0 * 64 + sub * 4];
        ax[0] += lo_f(v.x); ax[1] += hi_f(v.x);
        ax[2] += lo_f(v.y); ax[3] += hi_f(v.y);
        ax[4] += lo_f(v.z); ax[5] += hi_f(v.z);
        ax[6] += lo_f(v.w); ax[7] += hi_f(v.w);
    }
    #pragma unroll
    for (int d = 0; d < 8; d++) {
        ax[d] += __shfl_xor(ax[d], 16);
        ax[d] += __shfl_xor(ax[d], 32);
    }
    if (g == 0) {
        float dn = dinv[n];
        uint4 su = *(const uint4*)&tab[(size_t)n * 64 + sub * 4];
        ax[0] += lo_f(su.x); ax[1] += hi_f(su.x);
        ax[2] += lo_f(su.y); ax[3] += hi_f(su.y);
        ax[4] += lo_f(su.z); ax[5] += hi_f(su.z);
        ax[6] += lo_f(su.w); ax[7] += hi_f(su.w);
        float4 b0 = *(const float4*)&bias[sub * 8];
        float4 b1 = *(const float4*)&bias[sub * 8 + 4];
        ax[0] = b0.x + dn * ax[0]; ax[1] = b0.y + dn * ax[1];
        ax[2] = b0.z + dn * ax[2]; ax[3] = b0.w + dn * ax[3];
        ax[4] = b1.x + dn * ax[4]; ax[5] = b1.y + dn * ax[5];
        ax[6] = b1.z + dn * ax[6]; ax[7] = b1.w + dn * ax[7];
        if constexpr (DO_SELU) {
            #pragma unroll
            for (int d = 0; d < 8; d++) ax[d] = selu_f(ax[d]);
        }
        uint4 o;
        o.x = pack_pair(ax[0], ax[1]); o.y = pack_pair(ax[2], ax[3]);
        o.z = pack_pair(ax[4], ax[5]); o.w = pack_pair(ax[6], ax[7]);
        *(uint4*)&outp[(size_t)n * 64 + sub * 4] = o;
    }
}

// ---- 64-dim agg, wide: 8-lane group per edge ---------------------------
template <bool DO_SELU, bool DO_NORM, bool PACK>
__global__ void k_agg64w(const unsigned* __restrict__ tab, const int* __restrict__ rowptr,
                         const int* __restrict__ ecol, const float* __restrict__ dinv,
                         const float* __restrict__ bias, void* __restrict__ out_) {
    int n = (blockIdx.x * blockDim.x + threadIdx.x) >> 6;
    int l = threadIdx.x & 63;
    if (n >= NN) return;
    int g = l >> 3, sub = l & 7;
    int beg = rowptr[n], end = rowptr[n + 1];

    float ax[8] = {0.f, 0.f, 0.f, 0.f, 0.f, 0.f, 0.f, 0.f};
    int e = beg + g;
    for (; e + 8 < end; e += 16) {
        int s0 = ecol[e], s1 = ecol[e + 8];
        uint4 v0 = *(const uint4*)&tab[(size_t)s0 * 32 + sub * 4];
        uint4 v1 = *(const uint4*)&tab[(size_t)s1 * 32 + sub * 4];
        ax[0] += lo_f(v0.x); ax[1] += hi_f(v0.x);
        ax[2] += lo_f(v0.y); ax[3] += hi_f(v0.y);
        ax[4] += lo_f(v0.z); ax[5] += hi_f(v0.z);
        ax[6] += lo_f(v0.w); ax[7] += hi_f(v0.w);
        ax[0] += lo_f(v1.x); ax[1] += hi_f(v1.x);
        ax[2] += lo_f(v1.y); ax[3] += hi_f(v1.y);
        ax[4] += lo_f(v1.z); ax[5] += hi_f(v1.z);
        ax[6] += lo_f(v1.w); ax[7] += hi_f(v1.w);
    }
    for (; e < end; e += 8) {
        int s0 = ecol[e];
        uint4 v = *(const uint4*)&tab[(size_t)s0 * 32 + sub * 4];
        ax[0] += lo_f(v.x); ax[1] += hi_f(v.x);
        ax[2] += lo_f(v.y); ax[3] += hi_f(v.y);
        ax[4] += lo_f(v.z); ax[5] += hi_f(v.z);
        ax[6] += lo_f(v.w); ax[7] += hi_f(v.w);
    }
    #pragma unroll
    for (int d = 0; d < 8; d++) {
        ax[d] += __shfl_xor(ax[d], 8);
        ax[d] += __shfl_xor(ax[d], 16);
        ax[d] += __shfl_xor(ax[d], 32);
    }
    if (g == 0) {
        float dn = dinv[n];
        uint4 su = *(const uint4*)&tab[(size_t)n * 32 + sub * 4];
        ax[0] += lo_f(su.x); ax[1] += hi_f(su.x);
        ax[2] += lo_f(su.y); ax[3] += hi_f(su.y);
        ax[4] += lo_f(su.z); ax[5] += hi_f(su.z);
        ax[6] += lo_f(su.w); ax[7] += hi_f(su.w);
        float4 b0 = *(const float4*)&bias[sub * 8];
        float4 b1 = *(const float4*)&bias[sub * 8 + 4];
        ax[0] = b0.x + dn * ax[0]; ax[1] = b0.y + dn * ax[1];
        ax[2] = b0.z + dn * ax[2]; ax[3] = b0.w + dn * ax[3];
        ax[4] = b1.x + dn * ax[4]; ax[5] = b1.y + dn * ax[5];
        ax[6] = b1.z + dn * ax[6]; ax[7] = b1.w + dn * ax[7];
        if constexpr (DO_SELU) {
            #pragma unroll
            for (int d = 0; d < 8; d++) ax[d] = selu_f(ax[d]);
        }
        if constexpr (DO_NORM) {
            float ss = 0.f;
            #pragma unroll
            for (int d = 0; d < 8; d++) ss += ax[d] * ax[d];
            ss += __shfl_xor(ss, 1);
            ss += __shfl_xor(ss, 2);
            ss += __shfl_xor(ss, 4);
            float inv = 1.0f / fmaxf(sqrtf(ss), 1e-12f);
            #pragma unroll
            for (int d = 0; d < 8; d++) ax[d] *= inv;
        }
        if constexpr (PACK) {
            uint4 o;
            o.x = pack_pair(ax[0], ax[1]); o.y = pack_pair(ax[2], ax[3]);
            o.z = pack_pair(ax[4], ax[5]); o.w = pack_pair(ax[6], ax[7]);
            *(uint4*)&((unsigned*)out_)[(size_t)n * 32 + sub * 4] = o;
        } else {
            float* op = (float*)out_ + (size_t)n * 64 + sub * 8;
            *(float4*)op = make_float4(ax[0], ax[1], ax[2], ax[3]);
            *(float4*)(op + 4) = make_float4(ax[4], ax[5], ax[6], ax[7]);
        }
    }
}

extern "C" void kernel_launch(void* const* d_in, const int* in_sizes, int n_in,
                              void* d_out, int out_size, void* d_ws, size_t ws_size,
                              hipStream_t stream) {
    const float* x  = (const float*)d_in[0];
    const int* edge = (const int*)d_in[1];
    const float* W1 = (const float*)d_in[2]; const float* b1 = (const float*)d_in[3];
    const float* W2 = (const float*)d_in[4]; const float* b2 = (const float*)d_in[5];
    const float* W3 = (const float*)d_in[6]; const float* b3 = (const float*)d_in[7];
    const float* W4 = (const float*)d_in[8]; const float* b4 = (const float*)d_in[9];
    float* out = (float*)d_out;

    char* ws = (char*)d_ws;
    size_t off = 0;
    auto alloc = [&](size_t bytes) -> void* {
        void* p = ws + off;
        off = (off + bytes + 255) & ~(size_t)255;
        return p;
    };
    // table buffers padded by 128 rows: k_mm4's last block overreads harmlessly
    int*      rowptr = (int*)alloc((size_t)(NN + 1) * 4);
    float*    dinv   = (float*)alloc((size_t)NN * 4);
    int*      tmp    = (int*)alloc((size_t)NE * 4);
    int*      ecol   = (int*)alloc((size_t)NE * 4);
    unsigned* tab    = (unsigned*)alloc((size_t)(NN + 128) * 64 * 4);
    unsigned* bufU   = (unsigned*)alloc((size_t)(NN + 128) * 64 * 4);
    unsigned* Wp     = (unsigned*)alloc((size_t)22528 * 4);
    int*      bhist  = (int*)alloc((size_t)NBK * 4);
    int*      bbase  = (int*)alloc((size_t)(NBK + 1) * 4);
    int*      bcur   = (int*)alloc((size_t)NBK * 16 * 4);

    const int* srcp = edge;
    const int* dstp = edge + NE;

    hipMemsetAsync(bhist, 0, (size_t)NBK * 4, stream);
    k_histB<<<BINA_BLOCKS, 256, 0, stream>>>(dstp, bhist);
    k_scanBkt<<<1, 256, 0, stream>>>(bhist, bbase, bcur, rowptr);
    k_binA<<<BINA_BLOCKS, 256, 0, stream>>>(srcp, dstp, bcur, tmp);
    k_cntB<<<NBK, 256, 0, stream>>>(tmp, bbase, rowptr, dinv, ecol);

    const int AGG_B = (NN + 3) / 4;       // 4 waves/block, 1 wave/node
    const int MMB = (NN + 127) / 128;     // 128-row MFMA tiles

    k_packw<<<88, 256, 0, stream>>>(W1, W2, W3, W4, Wp);

    // layer 1: x(128) -> 128, selu  (f32 input fused-packed in mm4)
    k_mm4<128, 128, true><<<MMB, 256, 0, stream>>>(x, Wp, dinv, tab);
    k_agg128w<true><<<AGG_B, 256, 0, stream>>>(tab, rowptr, ecol, dinv, b1, bufU);
    // layer 2: 128 -> 128, selu
    k_mm4<128, 128, false><<<MMB, 256, 0, stream>>>(bufU, Wp + 8192, dinv, tab);
    k_agg128w<true><<<AGG_B, 256, 0, stream>>>(tab, rowptr, ecol, dinv, b2, bufU);
    // layer 3: 128 -> 64, selu
    k_mm4<128, 64, false><<<MMB, 256, 0, stream>>>(bufU, Wp + 16384, dinv, tab);
    k_agg64w<true, false, true><<<AGG_B, 256, 0, stream>>>(tab, rowptr, ecol, dinv, b3, bufU);
    // layer 4: 64 -> 64, no selu, L2-normalize, straight to d_out
    k_mm4<64, 64, false><<<MMB, 256, 0, stream>>>(bufU, Wp + 20480, dinv, tab);
    k_agg64w<false, true, false><<<AGG_B, 256, 0, stream>>>(tab, rowptr, ecol, dinv, b4, out);
}